// Round 1
// baseline (278.265 us; speedup 1.0000x reference)
//
#include <hip/hip_runtime.h>
#include <hip/hip_bf16.h>

#define SEQ 2048
#define HD 64

typedef __bf16 bf16x8 __attribute__((ext_vector_type(8)));
typedef float f32x4 __attribute__((ext_vector_type(4)));

// Flash attention fwd, causal, D=64, fp32 in/out, bf16 MFMA compute.
// Block = 256 threads (4 waves); block covers 64 q rows of one (b,h).
// Wave w covers q rows [q0+16w, q0+16w+16). KV tiles of 64 rows.
__global__ void fattn_kernel(const float* __restrict__ Q,
                             const float* __restrict__ K,
                             const float* __restrict__ V,
                             float* __restrict__ O) {
  // K tile: [64][64] bf16, row stride 128B, XOR-swizzled 16B slots within row.
  __shared__ __align__(16) unsigned short sK[64 * 64];
  // V^T tile: [d=64][j], row stride 72 elems (144B) for bank spread + 16B align.
  __shared__ __align__(16) unsigned short sVt[64 * 72];
  // Per-wave P tile: [16 rows i][64 cols j], stride 72.
  __shared__ __align__(16) unsigned short sP[4][16 * 72];

  const int tid = threadIdx.x;
  const int wid = tid >> 6;
  const int lane = tid & 63;
  const int g = lane >> 4;    // 16-lane group 0..3
  const int lx = lane & 15;

  const int qb = (int)gridDim.x - 1 - (int)blockIdx.x;  // long blocks first
  const int bh = blockIdx.y;
  const int q0 = qb * 64;

  const size_t base = (size_t)bh * SEQ * HD;
  const float* Qp = Q + base;
  const float* Kp = K + base;
  const float* Vp = V + base;
  float* Op = O + base;

  // ---- Q fragments, scale folded in. A-layout: lane holds Q[lx][8g+32c+e].
  bf16x8 qf[2];
  {
    const int row = q0 + wid * 16 + lx;
    const float* qr = Qp + (size_t)row * HD + 8 * g;
#pragma unroll
    for (int c = 0; c < 2; ++c) {
      float4 a = *(const float4*)(qr + 32 * c);
      float4 b = *(const float4*)(qr + 32 * c + 4);
      bf16x8 w;
      w[0] = (__bf16)(a.x * 0.125f);
      w[1] = (__bf16)(a.y * 0.125f);
      w[2] = (__bf16)(a.z * 0.125f);
      w[3] = (__bf16)(a.w * 0.125f);
      w[4] = (__bf16)(b.x * 0.125f);
      w[5] = (__bf16)(b.y * 0.125f);
      w[6] = (__bf16)(b.z * 0.125f);
      w[7] = (__bf16)(b.w * 0.125f);
      qf[c] = w;
    }
  }

  f32x4 acc[4];  // O tiles: acc[dt][r] = O[i=4g+r][d=lx+16dt]
#pragma unroll
  for (int dt = 0; dt < 4; ++dt) acc[dt] = (f32x4){0.f, 0.f, 0.f, 0.f};
  float m_run[4], l_run[4];
#pragma unroll
  for (int r = 0; r < 4; ++r) { m_run[r] = -1e30f; l_run[r] = 0.f; }

  const int iw0 = q0 + wid * 16;
  const int nkb = qb + 1;  // causal: kv tiles with j0 <= q0+63

  for (int kb = 0; kb < nkb; ++kb) {
    const int j0 = kb * 64;
    __syncthreads();  // previous iteration's LDS reads done

    // ---- stage K (bf16, swizzled) and V^T (bf16) ----
    {
      const int jr = tid >> 2;           // kv row 0..63
      const int d0 = (tid & 3) * 16;     // d chunk
      const float* src = Kp + (size_t)(j0 + jr) * HD + d0;
#pragma unroll
      for (int h = 0; h < 2; ++h) {
        float4 a = *(const float4*)(src + 8 * h);
        float4 b = *(const float4*)(src + 8 * h + 4);
        bf16x8 w;
        w[0] = (__bf16)a.x; w[1] = (__bf16)a.y; w[2] = (__bf16)a.z; w[3] = (__bf16)a.w;
        w[4] = (__bf16)b.x; w[5] = (__bf16)b.y; w[6] = (__bf16)b.z; w[7] = (__bf16)b.w;
        const int byteoff = ((d0 + 8 * h) * 2) ^ ((jr & 7) << 4);
        *(bf16x8*)((char*)sK + jr * 128 + byteoff) = w;
      }
      const float* vsrc = Vp + (size_t)(j0 + jr) * HD + d0;
#pragma unroll
      for (int h = 0; h < 4; ++h) {
        float4 a = *(const float4*)(vsrc + 4 * h);
        sVt[(d0 + 4 * h + 0) * 72 + jr] = __builtin_bit_cast(unsigned short, (__bf16)a.x);
        sVt[(d0 + 4 * h + 1) * 72 + jr] = __builtin_bit_cast(unsigned short, (__bf16)a.y);
        sVt[(d0 + 4 * h + 2) * 72 + jr] = __builtin_bit_cast(unsigned short, (__bf16)a.z);
        sVt[(d0 + 4 * h + 3) * 72 + jr] = __builtin_bit_cast(unsigned short, (__bf16)a.w);
      }
    }
    __syncthreads();

    // ---- S = QK^T: four 16x16 j-tiles, K=64 via 2 MFMA ----
    float s[4][4];  // [jt][r], element S[i=4g+r][j=jt*16+lx]
#pragma unroll
    for (int jt = 0; jt < 4; ++jt) {
      f32x4 c = (f32x4){0.f, 0.f, 0.f, 0.f};
#pragma unroll
      for (int cc = 0; cc < 2; ++cc) {
        const int row = jt * 16 + lx;
        const int byteoff = (16 * g + 64 * cc) ^ ((row & 7) << 4);
        bf16x8 kf = *(const bf16x8*)((const char*)sK + row * 128 + byteoff);
        c = __builtin_amdgcn_mfma_f32_16x16x32_bf16(qf[cc], kf, c, 0, 0, 0);
      }
      const int jg = j0 + jt * 16 + lx;
#pragma unroll
      for (int r = 0; r < 4; ++r) {
        const int ig = iw0 + 4 * g + r;
        s[jt][r] = (jg <= ig) ? c[r] : -1e30f;
      }
    }

    // ---- online softmax (row = 4g+r; j spread over 16 lanes x 4 jt) ----
#pragma unroll
    for (int r = 0; r < 4; ++r) {
      float mt = fmaxf(fmaxf(s[0][r], s[1][r]), fmaxf(s[2][r], s[3][r]));
#pragma unroll
      for (int msk = 1; msk <= 8; msk <<= 1) mt = fmaxf(mt, __shfl_xor(mt, msk));
      const float mn = fmaxf(m_run[r], mt);
      const float alpha = __expf(m_run[r] - mn);
      m_run[r] = mn;
      float rs = 0.f;
#pragma unroll
      for (int jt = 0; jt < 4; ++jt) {
        const float p = __expf(s[jt][r] - mn);
        s[jt][r] = p;
        rs += p;
      }
#pragma unroll
      for (int msk = 1; msk <= 8; msk <<= 1) rs += __shfl_xor(rs, msk);
      l_run[r] = l_run[r] * alpha + rs;
#pragma unroll
      for (int dt = 0; dt < 4; ++dt) acc[dt][r] *= alpha;
    }

    // ---- P (bf16) to per-wave LDS, then PV ----
#pragma unroll
    for (int jt = 0; jt < 4; ++jt)
#pragma unroll
      for (int r = 0; r < 4; ++r)
        sP[wid][(4 * g + r) * 72 + jt * 16 + lx] =
            __builtin_bit_cast(unsigned short, (__bf16)s[jt][r]);
    asm volatile("s_waitcnt lgkmcnt(0)" ::: "memory");

#pragma unroll
    for (int cc = 0; cc < 2; ++cc) {
      bf16x8 pf = *(const bf16x8*)(&sP[wid][lx * 72 + 8 * g + 32 * cc]);
#pragma unroll
      for (int dt = 0; dt < 4; ++dt) {
        bf16x8 vf = *(const bf16x8*)(&sVt[(lx + 16 * dt) * 72 + 8 * g + 32 * cc]);
        acc[dt] = __builtin_amdgcn_mfma_f32_16x16x32_bf16(pf, vf, acc[dt], 0, 0, 0);
      }
    }
  }

  // ---- epilogue: O = acc / l ----
#pragma unroll
  for (int r = 0; r < 4; ++r) {
    const float inv = 1.f / l_run[r];
    const int ig = q0 + wid * 16 + 4 * g + r;
    float* orow = Op + (size_t)ig * HD + lx;
#pragma unroll
    for (int dt = 0; dt < 4; ++dt) orow[16 * dt] = acc[dt][r] * inv;
  }
}

extern "C" void kernel_launch(void* const* d_in, const int* in_sizes, int n_in,
                              void* d_out, int out_size, void* d_ws, size_t ws_size,
                              hipStream_t stream) {
  const float* q = (const float*)d_in[0];
  const float* k = (const float*)d_in[1];
  const float* v = (const float*)d_in[2];
  float* o = (float*)d_out;
  dim3 grid(SEQ / 64, 64);  // 32 q-blocks x (B*H)
  fattn_kernel<<<grid, 256, 0, stream>>>(q, k, v, o);
}

// Round 2
// 225.424 us; speedup vs baseline: 1.2344x; 1.2344x over previous
//
#include <hip/hip_runtime.h>
#include <hip/hip_bf16.h>

#define SEQ 2048
#define HD 64

typedef __bf16 bf16x8 __attribute__((ext_vector_type(8)));
typedef float f32x4 __attribute__((ext_vector_type(4)));

typedef const __attribute__((address_space(1))) void gvoid_t;
typedef __attribute__((address_space(3))) void svoid_t;

__device__ __forceinline__ void gload_lds16(const void* g, void* l) {
  // HW writes LDS at (uniform base + lane*16); global src is per-lane.
  __builtin_amdgcn_global_load_lds((gvoid_t*)g, (svoid_t*)l, 16, 0, 0);
}

__device__ __forceinline__ bf16x8 cvt8(const float* p) {
  float4 a = *(const float4*)p;
  float4 b = *(const float4*)(p + 4);
  bf16x8 w;
  w[0] = (__bf16)a.x; w[1] = (__bf16)a.y; w[2] = (__bf16)a.z; w[3] = (__bf16)a.w;
  w[4] = (__bf16)b.x; w[5] = (__bf16)b.y; w[6] = (__bf16)b.z; w[7] = (__bf16)b.w;
  return w;
}

// ---------------------------------------------------------------------------
// Pre-pass: K -> bf16 rows with XOR-swizzle baked into global layout;
//           V -> V^T bf16 rows ([bh][d][SEQ]) with XOR-swizzle per 64-j segment.
// Layouts (content contracts used by the main kernel):
//   Kswz[bh][j][16B chunk c] = Kbf16[j][8*(c ^ (j&7)) .. +8)
//   Vt  [bh][d][j0 + 8c ..]  = Vbf16[j0 + 8*(c ^ (d&7)) .. +8)][d]
// so a LINEAR global_load_lds of a 64-row tile yields LDS where
//   LDS[row][byte b] = X[row][(b ^ ((row&7)<<4)) >> 1]   (conflict-free reads)
// ---------------------------------------------------------------------------
__global__ void prep_kernel(const float* __restrict__ K,
                            const float* __restrict__ V,
                            unsigned short* __restrict__ Kswz,
                            unsigned short* __restrict__ Vt) {
  __shared__ __align__(16) unsigned short sT[64 * 72];  // V^T tile, stride 72
  const int t = threadIdx.x;
  const int kb = blockIdx.x;  // 0..31
  const int bh = blockIdx.y;
  const int j0 = kb * 64;
  const size_t ibase = (size_t)bh * SEQ * HD;

  // ---- K: convert + swizzle within each 128B row ----
  {
    const int j = t >> 2;       // 0..63
    const int m = (t & 3) * 2;  // chunk index 0,2,4,6
    const float* src = K + ibase + (size_t)(j0 + j) * HD + m * 8;
    unsigned short* dst = Kswz + ibase + (size_t)(j0 + j) * HD;
#pragma unroll
    for (int h = 0; h < 2; ++h) {
      bf16x8 w = cvt8(src + 8 * h);
      const int c = (m + h) ^ (j & 7);
      *(bf16x8*)(dst + c * 8) = w;
    }
  }
  // ---- V: transpose 64x64 tile via LDS ----
  {
    const int jr = t >> 2;
    const int d0 = (t & 3) * 16;
    const float* vsrc = V + ibase + (size_t)(j0 + jr) * HD + d0;
#pragma unroll
    for (int h = 0; h < 4; ++h) {
      float4 a = *(const float4*)(vsrc + 4 * h);
      sT[(d0 + 4 * h + 0) * 72 + jr] = __builtin_bit_cast(unsigned short, (__bf16)a.x);
      sT[(d0 + 4 * h + 1) * 72 + jr] = __builtin_bit_cast(unsigned short, (__bf16)a.y);
      sT[(d0 + 4 * h + 2) * 72 + jr] = __builtin_bit_cast(unsigned short, (__bf16)a.z);
      sT[(d0 + 4 * h + 3) * 72 + jr] = __builtin_bit_cast(unsigned short, (__bf16)a.w);
    }
  }
  __syncthreads();
  {
#pragma unroll
    for (int p = 0; p < 2; ++p) {
      const int cid = t + 256 * p;  // 0..511
      const int d = cid >> 3;
      const int jj = cid & 7;
      bf16x8 w = *(const bf16x8*)(&sT[d * 72 + 8 * jj]);
      const int c = jj ^ (d & 7);
      *(bf16x8*)(Vt + (size_t)bh * HD * SEQ + (size_t)d * SEQ + j0 + c * 8) = w;
    }
  }
}

// ---------------------------------------------------------------------------
// Main: flash attention, causal, bf16 MFMA, double-buffered gload_lds staging.
// Block = 4 waves, 64 q rows; KV tiles of 64.
// ---------------------------------------------------------------------------
__global__ void fattn_kernel(const float* __restrict__ Q,
                             const unsigned short* __restrict__ Kswz,
                             const unsigned short* __restrict__ Vt,
                             float* __restrict__ O) {
  // double buffer: [buf][ K tile 4096 | V^T tile 4096 ] ushorts
  __shared__ __align__(16) unsigned short sbuf[2][2 * 64 * 64];
  __shared__ __align__(16) unsigned short sP[4][16 * 72];

  const int tid = threadIdx.x;
  const int wid = tid >> 6;
  const int lane = tid & 63;
  const int g = lane >> 4;
  const int lx = lane & 15;

  const int qb = (int)gridDim.x - 1 - (int)blockIdx.x;  // long blocks first
  const int bh = blockIdx.y;
  const int q0 = qb * 64;

  const float* Qp = Q + (size_t)bh * SEQ * HD;
  const unsigned short* Kg = Kswz + (size_t)bh * SEQ * HD;
  const unsigned short* Vg = Vt + (size_t)bh * HD * SEQ;
  float* Op = O + (size_t)bh * SEQ * HD;

  // ---- Q fragments (scale folded) : lane holds Q[lx][8g+32c+e] ----
  bf16x8 qf[2];
  {
    const int row = q0 + wid * 16 + lx;
    const float* qr = Qp + (size_t)row * HD + 8 * g;
#pragma unroll
    for (int c = 0; c < 2; ++c) {
      float4 a = *(const float4*)(qr + 32 * c);
      float4 b = *(const float4*)(qr + 32 * c + 4);
      bf16x8 w;
      w[0] = (__bf16)(a.x * 0.125f); w[1] = (__bf16)(a.y * 0.125f);
      w[2] = (__bf16)(a.z * 0.125f); w[3] = (__bf16)(a.w * 0.125f);
      w[4] = (__bf16)(b.x * 0.125f); w[5] = (__bf16)(b.y * 0.125f);
      w[6] = (__bf16)(b.z * 0.125f); w[7] = (__bf16)(b.w * 0.125f);
      qf[c] = w;
    }
  }

  f32x4 acc[4];
#pragma unroll
  for (int dt = 0; dt < 4; ++dt) acc[dt] = (f32x4){0.f, 0.f, 0.f, 0.f};
  float m_run[4], l_run[4];
#pragma unroll
  for (int r = 0; r < 4; ++r) { m_run[r] = -1e30f; l_run[r] = 0.f; }

  const int iw0 = q0 + wid * 16;
  const int nkb = qb + 1;

  // ---- staging: 2 K-rows-groups + 2 Vt-rows-groups per wave (gload_lds x4) ----
  auto stage = [&](int buf, int j0s) {
    unsigned short* bK = &sbuf[buf][0];
    unsigned short* bV = &sbuf[buf][4096];
#pragma unroll
    for (int tt = 0; tt < 2; ++tt) {
      const int row = 16 * wid + 8 * tt;  // uniform per wave
      const unsigned short* gk =
          Kg + (size_t)(j0s + row + (lane >> 3)) * HD + (lane & 7) * 8;
      gload_lds16(gk, bK + row * HD);
      const unsigned short* gv =
          Vg + (size_t)(row + (lane >> 3)) * SEQ + j0s + (lane & 7) * 8;
      gload_lds16(gv, bV + row * HD);
    }
  };

  stage(0, 0);
  asm volatile("s_waitcnt vmcnt(0)" ::: "memory");
  __syncthreads();

  int cur = 0;
  for (int kb = 0; kb < nkb; ++kb) {
    const int j0 = kb * 64;
    if (kb + 1 < nkb) stage(cur ^ 1, j0 + 64);  // prefetch next tile

    const unsigned short* bK = &sbuf[cur][0];
    const unsigned short* bV = &sbuf[cur][4096];

    // ---- S = QK^T ----
    float s[4][4];
#pragma unroll
    for (int jt = 0; jt < 4; ++jt) {
      f32x4 c = (f32x4){0.f, 0.f, 0.f, 0.f};
#pragma unroll
      for (int cc = 0; cc < 2; ++cc) {
        const int row = jt * 16 + lx;
        const int byteoff = (16 * g + 64 * cc) ^ ((row & 7) << 4);
        bf16x8 kf = *(const bf16x8*)((const char*)bK + row * 128 + byteoff);
        c = __builtin_amdgcn_mfma_f32_16x16x32_bf16(qf[cc], kf, c, 0, 0, 0);
      }
      const int jg = j0 + jt * 16 + lx;
#pragma unroll
      for (int r = 0; r < 4; ++r) {
        const int ig = iw0 + 4 * g + r;
        s[jt][r] = (jg <= ig) ? c[r] : -1e30f;
      }
    }

    // ---- online softmax ----
#pragma unroll
    for (int r = 0; r < 4; ++r) {
      float mt = fmaxf(fmaxf(s[0][r], s[1][r]), fmaxf(s[2][r], s[3][r]));
#pragma unroll
      for (int msk = 1; msk <= 8; msk <<= 1) mt = fmaxf(mt, __shfl_xor(mt, msk));
      const float mn = fmaxf(m_run[r], mt);
      const float alpha = __expf(m_run[r] - mn);
      m_run[r] = mn;
      float rs = 0.f;
#pragma unroll
      for (int jt = 0; jt < 4; ++jt) {
        const float p = __expf(s[jt][r] - mn);
        s[jt][r] = p;
        rs += p;
      }
#pragma unroll
      for (int msk = 1; msk <= 8; msk <<= 1) rs += __shfl_xor(rs, msk);
      l_run[r] = l_run[r] * alpha + rs;
#pragma unroll
      for (int dt = 0; dt < 4; ++dt) acc[dt][r] *= alpha;
    }

    // ---- P -> per-wave LDS, then PV ----
#pragma unroll
    for (int jt = 0; jt < 4; ++jt)
#pragma unroll
      for (int r = 0; r < 4; ++r)
        sP[wid][(4 * g + r) * 72 + jt * 16 + lx] =
            __builtin_bit_cast(unsigned short, (__bf16)s[jt][r]);
    asm volatile("s_waitcnt lgkmcnt(0)" ::: "memory");

#pragma unroll
    for (int cc = 0; cc < 2; ++cc) {
      bf16x8 pf = *(const bf16x8*)(&sP[wid][lx * 72 + 8 * g + 32 * cc]);
#pragma unroll
      for (int dt = 0; dt < 4; ++dt) {
        const int vrow = lx + 16 * dt;
        const int vboff = (16 * g + 64 * cc) ^ ((vrow & 7) << 4);
        bf16x8 vf = *(const bf16x8*)((const char*)bV + vrow * 128 + vboff);
        acc[dt] = __builtin_amdgcn_mfma_f32_16x16x32_bf16(pf, vf, acc[dt], 0, 0, 0);
      }
    }

    asm volatile("s_waitcnt vmcnt(0)" ::: "memory");
    __syncthreads();
    cur ^= 1;
  }

  // ---- epilogue ----
#pragma unroll
  for (int r = 0; r < 4; ++r) {
    const float inv = 1.f / l_run[r];
    const int ig = q0 + wid * 16 + 4 * g + r;
    float* orow = Op + (size_t)ig * HD + lx;
#pragma unroll
    for (int dt = 0; dt < 4; ++dt) orow[16 * dt] = acc[dt][r] * inv;
  }
}

// ---------------------------------------------------------------------------
// Fallback (verified round-1 kernel) in case ws_size is too small.
// ---------------------------------------------------------------------------
__global__ void fattn_fallback(const float* __restrict__ Q,
                               const float* __restrict__ K,
                               const float* __restrict__ V,
                               float* __restrict__ O) {
  __shared__ __align__(16) unsigned short sK[64 * 64];
  __shared__ __align__(16) unsigned short sVt[64 * 72];
  __shared__ __align__(16) unsigned short sP[4][16 * 72];

  const int tid = threadIdx.x;
  const int wid = tid >> 6;
  const int lane = tid & 63;
  const int g = lane >> 4;
  const int lx = lane & 15;

  const int qb = (int)gridDim.x - 1 - (int)blockIdx.x;
  const int bh = blockIdx.y;
  const int q0 = qb * 64;

  const size_t base = (size_t)bh * SEQ * HD;
  const float* Qp = Q + base;
  const float* Kp = K + base;
  const float* Vp = V + base;
  float* Op = O + base;

  bf16x8 qf[2];
  {
    const int row = q0 + wid * 16 + lx;
    const float* qr = Qp + (size_t)row * HD + 8 * g;
#pragma unroll
    for (int c = 0; c < 2; ++c) {
      float4 a = *(const float4*)(qr + 32 * c);
      float4 b = *(const float4*)(qr + 32 * c + 4);
      bf16x8 w;
      w[0] = (__bf16)(a.x * 0.125f); w[1] = (__bf16)(a.y * 0.125f);
      w[2] = (__bf16)(a.z * 0.125f); w[3] = (__bf16)(a.w * 0.125f);
      w[4] = (__bf16)(b.x * 0.125f); w[5] = (__bf16)(b.y * 0.125f);
      w[6] = (__bf16)(b.z * 0.125f); w[7] = (__bf16)(b.w * 0.125f);
      qf[c] = w;
    }
  }

  f32x4 acc[4];
#pragma unroll
  for (int dt = 0; dt < 4; ++dt) acc[dt] = (f32x4){0.f, 0.f, 0.f, 0.f};
  float m_run[4], l_run[4];
#pragma unroll
  for (int r = 0; r < 4; ++r) { m_run[r] = -1e30f; l_run[r] = 0.f; }

  const int iw0 = q0 + wid * 16;
  const int nkb = qb + 1;

  for (int kb = 0; kb < nkb; ++kb) {
    const int j0 = kb * 64;
    __syncthreads();
    {
      const int jr = tid >> 2;
      const int d0 = (tid & 3) * 16;
      const float* src = Kp + (size_t)(j0 + jr) * HD + d0;
#pragma unroll
      for (int h = 0; h < 2; ++h) {
        bf16x8 w = cvt8(src + 8 * h);
        const int byteoff = ((d0 + 8 * h) * 2) ^ ((jr & 7) << 4);
        *(bf16x8*)((char*)sK + jr * 128 + byteoff) = w;
      }
      const float* vsrc = Vp + (size_t)(j0 + jr) * HD + d0;
#pragma unroll
      for (int h = 0; h < 4; ++h) {
        float4 a = *(const float4*)(vsrc + 4 * h);
        sVt[(d0 + 4 * h + 0) * 72 + jr] = __builtin_bit_cast(unsigned short, (__bf16)a.x);
        sVt[(d0 + 4 * h + 1) * 72 + jr] = __builtin_bit_cast(unsigned short, (__bf16)a.y);
        sVt[(d0 + 4 * h + 2) * 72 + jr] = __builtin_bit_cast(unsigned short, (__bf16)a.z);
        sVt[(d0 + 4 * h + 3) * 72 + jr] = __builtin_bit_cast(unsigned short, (__bf16)a.w);
      }
    }
    __syncthreads();

    float s[4][4];
#pragma unroll
    for (int jt = 0; jt < 4; ++jt) {
      f32x4 c = (f32x4){0.f, 0.f, 0.f, 0.f};
#pragma unroll
      for (int cc = 0; cc < 2; ++cc) {
        const int row = jt * 16 + lx;
        const int byteoff = (16 * g + 64 * cc) ^ ((row & 7) << 4);
        bf16x8 kf = *(const bf16x8*)((const char*)sK + row * 128 + byteoff);
        c = __builtin_amdgcn_mfma_f32_16x16x32_bf16(qf[cc], kf, c, 0, 0, 0);
      }
      const int jg = j0 + jt * 16 + lx;
#pragma unroll
      for (int r = 0; r < 4; ++r) {
        const int ig = iw0 + 4 * g + r;
        s[jt][r] = (jg <= ig) ? c[r] : -1e30f;
      }
    }

#pragma unroll
    for (int r = 0; r < 4; ++r) {
      float mt = fmaxf(fmaxf(s[0][r], s[1][r]), fmaxf(s[2][r], s[3][r]));
#pragma unroll
      for (int msk = 1; msk <= 8; msk <<= 1) mt = fmaxf(mt, __shfl_xor(mt, msk));
      const float mn = fmaxf(m_run[r], mt);
      const float alpha = __expf(m_run[r] - mn);
      m_run[r] = mn;
      float rs = 0.f;
#pragma unroll
      for (int jt = 0; jt < 4; ++jt) {
        const float p = __expf(s[jt][r] - mn);
        s[jt][r] = p;
        rs += p;
      }
#pragma unroll
      for (int msk = 1; msk <= 8; msk <<= 1) rs += __shfl_xor(rs, msk);
      l_run[r] = l_run[r] * alpha + rs;
#pragma unroll
      for (int dt = 0; dt < 4; ++dt) acc[dt][r] *= alpha;
    }

#pragma unroll
    for (int jt = 0; jt < 4; ++jt)
#pragma unroll
      for (int r = 0; r < 4; ++r)
        sP[wid][(4 * g + r) * 72 + jt * 16 + lx] =
            __builtin_bit_cast(unsigned short, (__bf16)s[jt][r]);
    asm volatile("s_waitcnt lgkmcnt(0)" ::: "memory");

#pragma unroll
    for (int cc = 0; cc < 2; ++cc) {
      bf16x8 pf = *(const bf16x8*)(&sP[wid][lx * 72 + 8 * g + 32 * cc]);
#pragma unroll
      for (int dt = 0; dt < 4; ++dt) {
        bf16x8 vf = *(const bf16x8*)(&sVt[(lx + 16 * dt) * 72 + 8 * g + 32 * cc]);
        acc[dt] = __builtin_amdgcn_mfma_f32_16x16x32_bf16(pf, vf, acc[dt], 0, 0, 0);
      }
    }
  }

#pragma unroll
  for (int r = 0; r < 4; ++r) {
    const float inv = 1.f / l_run[r];
    const int ig = q0 + wid * 16 + 4 * g + r;
    float* orow = Op + (size_t)ig * HD + lx;
#pragma unroll
    for (int dt = 0; dt < 4; ++dt) orow[16 * dt] = acc[dt][r] * inv;
  }
}

extern "C" void kernel_launch(void* const* d_in, const int* in_sizes, int n_in,
                              void* d_out, int out_size, void* d_ws, size_t ws_size,
                              hipStream_t stream) {
  const float* q = (const float*)d_in[0];
  const float* k = (const float*)d_in[1];
  const float* v = (const float*)d_in[2];
  float* o = (float*)d_out;

  const size_t kv_elems = (size_t)64 * SEQ * HD;       // per-tensor bf16 elems
  const size_t need = 2 * kv_elems * sizeof(unsigned short);  // 32 MiB

  if (ws_size >= need) {
    unsigned short* kswz = (unsigned short*)d_ws;
    unsigned short* vt = kswz + kv_elems;
    dim3 pgrid(SEQ / 64, 64);
    prep_kernel<<<pgrid, 256, 0, stream>>>(k, v, kswz, vt);
    dim3 grid(SEQ / 64, 64);
    fattn_kernel<<<grid, 256, 0, stream>>>(q, kswz, vt, o);
  } else {
    dim3 grid(SEQ / 64, 64);
    fattn_fallback<<<grid, 256, 0, stream>>>(q, k, v, o);
  }
}

// Round 3
// 99.830 us; speedup vs baseline: 2.7874x; 2.2581x over previous
//
#include <hip/hip_runtime.h>
#include <hip/hip_bf16.h>

#define SEQ 2048
#define HD 64

typedef __bf16 bf16x8 __attribute__((ext_vector_type(8)));
typedef float f32x4 __attribute__((ext_vector_type(4)));
typedef float f32x16 __attribute__((ext_vector_type(16)));
typedef unsigned int u32x4 __attribute__((ext_vector_type(4)));

typedef const __attribute__((address_space(1))) void gvoid_t;
typedef __attribute__((address_space(3))) void svoid_t;

__device__ __forceinline__ void gload_lds16(const void* g, void* l) {
  __builtin_amdgcn_global_load_lds((gvoid_t*)g, (svoid_t*)l, 16, 0, 0);
}

__device__ __forceinline__ bf16x8 cvt8(const float* p) {
  float4 a = *(const float4*)p;
  float4 b = *(const float4*)(p + 4);
  bf16x8 w;
  w[0] = (__bf16)a.x; w[1] = (__bf16)a.y; w[2] = (__bf16)a.z; w[3] = (__bf16)a.w;
  w[4] = (__bf16)b.x; w[5] = (__bf16)b.y; w[6] = (__bf16)b.z; w[7] = (__bf16)b.w;
  return w;
}

__device__ __forceinline__ unsigned cvtpk_bf16(float lo, float hi) {
  unsigned r;
  asm("v_cvt_pk_bf16_f32 %0, %1, %2" : "=v"(r) : "v"(lo), "v"(hi));
  return r;
}

// ---------------------------------------------------------------------------
// Pre-pass (unchanged from R2, verified): K -> bf16 swizzled rows; V -> V^T
// bf16 [bh][d][SEQ] with per-64-j-segment swizzle keyed on (d&7).
// ---------------------------------------------------------------------------
__global__ void prep_kernel(const float* __restrict__ K,
                            const float* __restrict__ V,
                            unsigned short* __restrict__ Kswz,
                            unsigned short* __restrict__ Vt) {
  __shared__ __align__(16) unsigned short sT[64 * 72];
  const int t = threadIdx.x;
  const int kb = blockIdx.x;
  const int bh = blockIdx.y;
  const int j0 = kb * 64;
  const size_t ibase = (size_t)bh * SEQ * HD;

  {
    const int j = t >> 2;
    const int m = (t & 3) * 2;
    const float* src = K + ibase + (size_t)(j0 + j) * HD + m * 8;
    unsigned short* dst = Kswz + ibase + (size_t)(j0 + j) * HD;
#pragma unroll
    for (int h = 0; h < 2; ++h) {
      bf16x8 w = cvt8(src + 8 * h);
      const int c = (m + h) ^ (j & 7);
      *(bf16x8*)(dst + c * 8) = w;
    }
  }
  {
    const int jr = t >> 2;
    const int d0 = (t & 3) * 16;
    const float* vsrc = V + ibase + (size_t)(j0 + jr) * HD + d0;
#pragma unroll
    for (int h = 0; h < 4; ++h) {
      float4 a = *(const float4*)(vsrc + 4 * h);
      sT[(d0 + 4 * h + 0) * 72 + jr] = __builtin_bit_cast(unsigned short, (__bf16)a.x);
      sT[(d0 + 4 * h + 1) * 72 + jr] = __builtin_bit_cast(unsigned short, (__bf16)a.y);
      sT[(d0 + 4 * h + 2) * 72 + jr] = __builtin_bit_cast(unsigned short, (__bf16)a.z);
      sT[(d0 + 4 * h + 3) * 72 + jr] = __builtin_bit_cast(unsigned short, (__bf16)a.w);
    }
  }
  __syncthreads();
  {
#pragma unroll
    for (int p = 0; p < 2; ++p) {
      const int cid = t + 256 * p;
      const int d = cid >> 3;
      const int jj = cid & 7;
      bf16x8 w = *(const bf16x8*)(&sT[d * 72 + 8 * jj]);
      const int c = jj ^ (d & 7);
      *(bf16x8*)(Vt + (size_t)bh * HD * SEQ + (size_t)d * SEQ + j0 + c * 8) = w;
    }
  }
}

// ---------------------------------------------------------------------------
// Main: swapped-operand 32x32 MFMA flash attention, in-register softmax.
// Block = 4 waves; wave w owns q rows [qb*128 + 32w, +32). KV tiles of 64.
// QK:  S^T = mfma(K, Q)  -> lane holds row i=lane&31, j = crow(r,hi)+32jt
// PV:  O   = mfma(V^T,P) -> lane holds O[i=lane&31][d = crow(r,hi)+32dt]
// crow(r,hi) = (r&3) + 8*(r>>2) + 4*hi
// ---------------------------------------------------------------------------
__global__ void fattn_kernel(const float* __restrict__ Q,
                             const unsigned short* __restrict__ Kswz,
                             const unsigned short* __restrict__ Vt,
                             float* __restrict__ O) {
  __shared__ __align__(16) unsigned short sbuf[2][2 * 64 * 64];  // K | V^T

  const int tid = threadIdx.x;
  const int wid = tid >> 6;
  const int lane = tid & 63;
  const int l31 = lane & 31;
  const int hi = lane >> 5;

  const int qb = (int)gridDim.x - 1 - (int)blockIdx.x;  // long blocks first
  const int bh = blockIdx.y;
  const int q0 = qb * 128;
  const int i0w = q0 + wid * 32;
  const int ig = i0w + l31;  // this lane's q row

  const float* Qp = Q + (size_t)bh * SEQ * HD;
  const unsigned short* Kg = Kswz + (size_t)bh * SEQ * HD;
  const unsigned short* Vg = Vt + (size_t)bh * HD * SEQ;
  float* Op = O + (size_t)bh * SEQ * HD;

  // ---- Q fragments (B-operand layout), scale*log2e folded ----
  const float qscale = 0.125f * 1.44269504088896340736f;
  bf16x8 qf[4];
  {
    const float* qr = Qp + (size_t)ig * HD + 8 * hi;
#pragma unroll
    for (int c = 0; c < 4; ++c) {
      float4 a = *(const float4*)(qr + 16 * c);
      float4 b = *(const float4*)(qr + 16 * c + 4);
      bf16x8 w;
      w[0] = (__bf16)(a.x * qscale); w[1] = (__bf16)(a.y * qscale);
      w[2] = (__bf16)(a.z * qscale); w[3] = (__bf16)(a.w * qscale);
      w[4] = (__bf16)(b.x * qscale); w[5] = (__bf16)(b.y * qscale);
      w[6] = (__bf16)(b.z * qscale); w[7] = (__bf16)(b.w * qscale);
      qf[c] = w;
    }
  }

  f32x16 oA, oB;  // O accum: oA -> d=crow+0, oB -> d=crow+32
#pragma unroll
  for (int r = 0; r < 16; ++r) { oA[r] = 0.f; oB[r] = 0.f; }
  float m_run = -1e30f, l_run = 0.f;

  const int nkb = 2 * qb + 2;

  auto stage = [&](int buf, int j0s) {
    unsigned short* bK = &sbuf[buf][0];
    unsigned short* bV = &sbuf[buf][4096];
#pragma unroll
    for (int tt = 0; tt < 2; ++tt) {
      const int row = 16 * wid + 8 * tt;  // uniform per wave
      const unsigned short* gk =
          Kg + (size_t)(j0s + row + (lane >> 3)) * HD + (lane & 7) * 8;
      gload_lds16(gk, bK + row * HD);
      const unsigned short* gv =
          Vg + (size_t)(row + (lane >> 3)) * SEQ + j0s + (lane & 7) * 8;
      gload_lds16(gv, bV + row * HD);
    }
  };

  stage(0, 0);
  asm volatile("s_waitcnt vmcnt(0)" ::: "memory");
  __syncthreads();

  int cur = 0;
  for (int kb = 0; kb < nkb; ++kb) {
    const int j0 = kb * 64;
    if (kb + 1 < nkb) stage(cur ^ 1, j0 + 64);

    const unsigned short* bK = &sbuf[cur][0];
    const unsigned short* bV = &sbuf[cur][4096];

    // ---- S^T = K . Q^T : two 32-j subtiles, K-dim 64 via 4 mfma each ----
    f32x16 sA, sB;
#pragma unroll
    for (int r = 0; r < 16; ++r) { sA[r] = 0.f; sB[r] = 0.f; }
    const int swz = (l31 & 7) << 4;
#pragma unroll
    for (int c = 0; c < 4; ++c) {
      const int boff = 32 * c + 16 * hi;
      bf16x8 kf0 = *(const bf16x8*)((const char*)bK + l31 * 128 + (boff ^ swz));
      sA = __builtin_amdgcn_mfma_f32_32x32x16_bf16(kf0, qf[c], sA, 0, 0, 0);
      bf16x8 kf1 = *(const bf16x8*)((const char*)bK + (32 + l31) * 128 + (boff ^ swz));
      sB = __builtin_amdgcn_mfma_f32_32x32x16_bf16(kf1, qf[c], sB, 0, 0, 0);
    }

    // ---- causal mask (only needed near the diagonal; wave-uniform test) ----
    if (j0 + 63 > i0w) {
#pragma unroll
      for (int r = 0; r < 16; ++r) {
        const int jl = j0 + (r & 3) + 8 * (r >> 2) + 4 * hi;
        sA[r] = (jl <= ig) ? sA[r] : -1e30f;
        sB[r] = (jl + 32 <= ig) ? sB[r] : -1e30f;
      }
    }

    // ---- in-register online softmax (log2 domain), defer-max ----
    float pmax = sA[0];
#pragma unroll
    for (int r = 1; r < 16; ++r) pmax = fmaxf(pmax, sA[r]);
#pragma unroll
    for (int r = 0; r < 16; ++r) pmax = fmaxf(pmax, sB[r]);
    pmax = fmaxf(pmax, __shfl_xor(pmax, 32));

    if (!__all(pmax - m_run <= 10.0f)) {
      const float mn = fmaxf(m_run, pmax);
      const float al = __builtin_amdgcn_exp2f(m_run - mn);
      m_run = mn;
      l_run *= al;
#pragma unroll
      for (int r = 0; r < 16; ++r) { oA[r] *= al; oB[r] *= al; }
    }

    float rs = 0.f;
#pragma unroll
    for (int r = 0; r < 16; ++r) { sA[r] = __builtin_amdgcn_exp2f(sA[r] - m_run); rs += sA[r]; }
#pragma unroll
    for (int r = 0; r < 16; ++r) { sB[r] = __builtin_amdgcn_exp2f(sB[r] - m_run); rs += sB[r]; }
    rs += __shfl_xor(rs, 32);
    l_run += rs;

    // ---- P -> bf16 PV fragments in-register (cvt_pk + permlane32_swap) ----
    bf16x8 pfr[4];
#define MKFRAG(SV, BASE, DST)                                              \
    {                                                                      \
      unsigned a0 = cvtpk_bf16(SV[BASE + 0], SV[BASE + 1]);                \
      unsigned b0 = cvtpk_bf16(SV[BASE + 4], SV[BASE + 5]);                \
      asm("v_permlane32_swap_b32 %0, %1" : "+v"(a0), "+v"(b0));            \
      unsigned a1 = cvtpk_bf16(SV[BASE + 2], SV[BASE + 3]);                \
      unsigned b1 = cvtpk_bf16(SV[BASE + 6], SV[BASE + 7]);                \
      asm("v_permlane32_swap_b32 %0, %1" : "+v"(a1), "+v"(b1));            \
      u32x4 wv = {a0, a1, b0, b1};                                         \
      DST = __builtin_bit_cast(bf16x8, wv);                                \
    }
    MKFRAG(sA, 0, pfr[0])
    MKFRAG(sA, 8, pfr[1])
    MKFRAG(sB, 0, pfr[2])
    MKFRAG(sB, 8, pfr[3])
#undef MKFRAG

    // ---- O += V^T . P^T ----
#pragma unroll
    for (int ks = 0; ks < 4; ++ks) {
      const int vbo = 32 * ks + 16 * hi;
      bf16x8 vf0 = *(const bf16x8*)((const char*)bV + l31 * 128 + (vbo ^ swz));
      oA = __builtin_amdgcn_mfma_f32_32x32x16_bf16(vf0, pfr[ks], oA, 0, 0, 0);
      bf16x8 vf1 = *(const bf16x8*)((const char*)bV + (32 + l31) * 128 + (vbo ^ swz));
      oB = __builtin_amdgcn_mfma_f32_32x32x16_bf16(vf1, pfr[ks], oB, 0, 0, 0);
    }

    asm volatile("s_waitcnt vmcnt(0)" ::: "memory");
    __syncthreads();
    cur ^= 1;
  }

  // ---- epilogue: lane owns O row ig; d = crow(r,hi)+32dt ----
  const float inv = 1.f / l_run;
  float* orow = Op + (size_t)ig * HD;
#pragma unroll
  for (int q2 = 0; q2 < 4; ++q2) {
    float4 o;
    o.x = oA[4 * q2 + 0] * inv; o.y = oA[4 * q2 + 1] * inv;
    o.z = oA[4 * q2 + 2] * inv; o.w = oA[4 * q2 + 3] * inv;
    *(float4*)(orow + 8 * q2 + 4 * hi) = o;
    float4 p;
    p.x = oB[4 * q2 + 0] * inv; p.y = oB[4 * q2 + 1] * inv;
    p.z = oB[4 * q2 + 2] * inv; p.w = oB[4 * q2 + 3] * inv;
    *(float4*)(orow + 32 + 8 * q2 + 4 * hi) = p;
  }
}

// ---------------------------------------------------------------------------
// Fallback (verified round-1 kernel) in case ws_size is too small.
// ---------------------------------------------------------------------------
__global__ void fattn_fallback(const float* __restrict__ Q,
                               const float* __restrict__ K,
                               const float* __restrict__ V,
                               float* __restrict__ O) {
  __shared__ __align__(16) unsigned short sK[64 * 64];
  __shared__ __align__(16) unsigned short sVt[64 * 72];
  __shared__ __align__(16) unsigned short sP[4][16 * 72];

  const int tid = threadIdx.x;
  const int wid = tid >> 6;
  const int lane = tid & 63;
  const int g = lane >> 4;
  const int lx = lane & 15;

  const int qb = (int)gridDim.x - 1 - (int)blockIdx.x;
  const int bh = blockIdx.y;
  const int q0 = qb * 64;

  const size_t base = (size_t)bh * SEQ * HD;
  const float* Qp = Q + base;
  const float* Kp = K + base;
  const float* Vp = V + base;
  float* Op = O + base;

  bf16x8 qf[2];
  {
    const int row = q0 + wid * 16 + lx;
    const float* qr = Qp + (size_t)row * HD + 8 * g;
#pragma unroll
    for (int c = 0; c < 2; ++c) {
      float4 a = *(const float4*)(qr + 32 * c);
      float4 b = *(const float4*)(qr + 32 * c + 4);
      bf16x8 w;
      w[0] = (__bf16)(a.x * 0.125f); w[1] = (__bf16)(a.y * 0.125f);
      w[2] = (__bf16)(a.z * 0.125f); w[3] = (__bf16)(a.w * 0.125f);
      w[4] = (__bf16)(b.x * 0.125f); w[5] = (__bf16)(b.y * 0.125f);
      w[6] = (__bf16)(b.z * 0.125f); w[7] = (__bf16)(b.w * 0.125f);
      qf[c] = w;
    }
  }

  f32x4 acc[4];
#pragma unroll
  for (int dt = 0; dt < 4; ++dt) acc[dt] = (f32x4){0.f, 0.f, 0.f, 0.f};
  float m_run[4], l_run[4];
#pragma unroll
  for (int r = 0; r < 4; ++r) { m_run[r] = -1e30f; l_run[r] = 0.f; }

  const int iw0 = q0 + wid * 16;
  const int nkb = qb + 1;

  for (int kb = 0; kb < nkb; ++kb) {
    const int j0 = kb * 64;
    __syncthreads();
    {
      const int jr = tid >> 2;
      const int d0 = (tid & 3) * 16;
      const float* src = Kp + (size_t)(j0 + jr) * HD + d0;
#pragma unroll
      for (int h = 0; h < 2; ++h) {
        bf16x8 w = cvt8(src + 8 * h);
        const int byteoff = ((d0 + 8 * h) * 2) ^ ((jr & 7) << 4);
        *(bf16x8*)((char*)sK + jr * 128 + byteoff) = w;
      }
      const float* vsrc = Vp + (size_t)(j0 + jr) * HD + d0;
#pragma unroll
      for (int h = 0; h < 4; ++h) {
        float4 a = *(const float4*)(vsrc + 4 * h);
        sVt[(d0 + 4 * h + 0) * 72 + jr] = __builtin_bit_cast(unsigned short, (__bf16)a.x);
        sVt[(d0 + 4 * h + 1) * 72 + jr] = __builtin_bit_cast(unsigned short, (__bf16)a.y);
        sVt[(d0 + 4 * h + 2) * 72 + jr] = __builtin_bit_cast(unsigned short, (__bf16)a.z);
        sVt[(d0 + 4 * h + 3) * 72 + jr] = __builtin_bit_cast(unsigned short, (__bf16)a.w);
      }
    }
    __syncthreads();

    float s[4][4];
#pragma unroll
    for (int jt = 0; jt < 4; ++jt) {
      f32x4 c = (f32x4){0.f, 0.f, 0.f, 0.f};
#pragma unroll
      for (int cc = 0; cc < 2; ++cc) {
        const int row = jt * 16 + lx;
        const int byteoff = (16 * g + 64 * cc) ^ ((row & 7) << 4);
        bf16x8 kf = *(const bf16x8*)((const char*)sK + row * 128 + byteoff);
        c = __builtin_amdgcn_mfma_f32_16x16x32_bf16(qf[cc], kf, c, 0, 0, 0);
      }
      const int jg = j0 + jt * 16 + lx;
#pragma unroll
      for (int r = 0; r < 4; ++r) {
        const int igf = iw0 + 4 * g + r;
        s[jt][r] = (jg <= igf) ? c[r] : -1e30f;
      }
    }

#pragma unroll
    for (int r = 0; r < 4; ++r) {
      float mt = fmaxf(fmaxf(s[0][r], s[1][r]), fmaxf(s[2][r], s[3][r]));
#pragma unroll
      for (int msk = 1; msk <= 8; msk <<= 1) mt = fmaxf(mt, __shfl_xor(mt, msk));
      const float mn = fmaxf(m_run[r], mt);
      const float alpha = __expf(m_run[r] - mn);
      m_run[r] = mn;
      float rs = 0.f;
#pragma unroll
      for (int jt = 0; jt < 4; ++jt) {
        const float p = __expf(s[jt][r] - mn);
        s[jt][r] = p;
        rs += p;
      }
#pragma unroll
      for (int msk = 1; msk <= 8; msk <<= 1) rs += __shfl_xor(rs, msk);
      l_run[r] = l_run[r] * alpha + rs;
#pragma unroll
      for (int dt = 0; dt < 4; ++dt) acc[dt][r] *= alpha;
    }

#pragma unroll
    for (int jt = 0; jt < 4; ++jt)
#pragma unroll
      for (int r = 0; r < 4; ++r)
        sP[wid][(4 * g + r) * 72 + jt * 16 + lx] =
            __builtin_bit_cast(unsigned short, (__bf16)s[jt][r]);
    asm volatile("s_waitcnt lgkmcnt(0)" ::: "memory");

#pragma unroll
    for (int cc = 0; cc < 2; ++cc) {
      bf16x8 pf = *(const bf16x8*)(&sP[wid][lx * 72 + 8 * g + 32 * cc]);
#pragma unroll
      for (int dt = 0; dt < 4; ++dt) {
        bf16x8 vf = *(const bf16x8*)(&sVt[(lx + 16 * dt) * 72 + 8 * g + 32 * cc]);
        acc[dt] = __builtin_amdgcn_mfma_f32_16x16x32_bf16(pf, vf, acc[dt], 0, 0, 0);
      }
    }
  }

#pragma unroll
  for (int r = 0; r < 4; ++r) {
    const float inv = 1.f / l_run[r];
    const int igf = q0 + wid * 16 + 4 * g + r;
    float* orow = Op + (size_t)igf * HD + lx;
#pragma unroll
    for (int dt = 0; dt < 4; ++dt) orow[16 * dt] = acc[dt][r] * inv;
  }
}

extern "C" void kernel_launch(void* const* d_in, const int* in_sizes, int n_in,
                              void* d_out, int out_size, void* d_ws, size_t ws_size,
                              hipStream_t stream) {
  const float* q = (const float*)d_in[0];
  const float* k = (const float*)d_in[1];
  const float* v = (const float*)d_in[2];
  float* o = (float*)d_out;

  const size_t kv_elems = (size_t)64 * SEQ * HD;
  const size_t need = 2 * kv_elems * sizeof(unsigned short);  // 32 MiB

  if (ws_size >= need) {
    unsigned short* kswz = (unsigned short*)d_ws;
    unsigned short* vt = kswz + kv_elems;
    dim3 pgrid(SEQ / 64, 64);
    prep_kernel<<<pgrid, 256, 0, stream>>>(k, v, kswz, vt);
    dim3 grid(SEQ / 128, 64);
    fattn_kernel<<<grid, 256, 0, stream>>>(q, kswz, vt, o);
  } else {
    dim3 grid(SEQ / 64, 64);
    fattn_fallback<<<grid, 256, 0, stream>>>(q, k, v, o);
  }
}

// Round 4
// 89.283 us; speedup vs baseline: 3.1167x; 1.1181x over previous
//
#include <hip/hip_runtime.h>
#include <hip/hip_bf16.h>

#define SEQ 2048
#define HD 64
#define NQB (SEQ / 128)  // 16 q-tiles of 128 rows

typedef __bf16 bf16x8 __attribute__((ext_vector_type(8)));
typedef float f32x4 __attribute__((ext_vector_type(4)));
typedef float f32x16 __attribute__((ext_vector_type(16)));
typedef unsigned int u32x4 __attribute__((ext_vector_type(4)));

typedef const __attribute__((address_space(1))) void gvoid_t;
typedef __attribute__((address_space(3))) void svoid_t;

__device__ __forceinline__ void gload_lds16(const void* g, void* l) {
  __builtin_amdgcn_global_load_lds((gvoid_t*)g, (svoid_t*)l, 16, 0, 0);
}

__device__ __forceinline__ bf16x8 cvt8(const float* p) {
  float4 a = *(const float4*)p;
  float4 b = *(const float4*)(p + 4);
  bf16x8 w;
  w[0] = (__bf16)a.x; w[1] = (__bf16)a.y; w[2] = (__bf16)a.z; w[3] = (__bf16)a.w;
  w[4] = (__bf16)b.x; w[5] = (__bf16)b.y; w[6] = (__bf16)b.z; w[7] = (__bf16)b.w;
  return w;
}

__device__ __forceinline__ unsigned cvtpk_bf16(float lo, float hi) {
  unsigned r;
  asm("v_cvt_pk_bf16_f32 %0, %1, %2" : "=v"(r) : "v"(lo), "v"(hi));
  return r;
}

// pairwise-tree max / sum over an f32x16 (short dep chains)
__device__ __forceinline__ float tmax16(const f32x16& v) {
  float a0 = fmaxf(v[0], v[1]), a1 = fmaxf(v[2], v[3]);
  float a2 = fmaxf(v[4], v[5]), a3 = fmaxf(v[6], v[7]);
  float a4 = fmaxf(v[8], v[9]), a5 = fmaxf(v[10], v[11]);
  float a6 = fmaxf(v[12], v[13]), a7 = fmaxf(v[14], v[15]);
  float b0 = fmaxf(a0, a1), b1 = fmaxf(a2, a3), b2 = fmaxf(a4, a5), b3 = fmaxf(a6, a7);
  return fmaxf(fmaxf(b0, b1), fmaxf(b2, b3));
}

// ---------------------------------------------------------------------------
// Pre-pass (verified R2/R3): K -> bf16 swizzled rows; V -> V^T bf16
// [bh][d][SEQ] with per-64-j-segment swizzle keyed on (d&7).
// ---------------------------------------------------------------------------
__global__ void prep_kernel(const float* __restrict__ K,
                            const float* __restrict__ V,
                            unsigned short* __restrict__ Kswz,
                            unsigned short* __restrict__ Vt) {
  __shared__ __align__(16) unsigned short sT[64 * 72];
  const int t = threadIdx.x;
  const int kb = blockIdx.x;
  const int bh = blockIdx.y;
  const int j0 = kb * 64;
  const size_t ibase = (size_t)bh * SEQ * HD;

  {
    const int j = t >> 2;
    const int m = (t & 3) * 2;
    const float* src = K + ibase + (size_t)(j0 + j) * HD + m * 8;
    unsigned short* dst = Kswz + ibase + (size_t)(j0 + j) * HD;
#pragma unroll
    for (int h = 0; h < 2; ++h) {
      bf16x8 w = cvt8(src + 8 * h);
      const int c = (m + h) ^ (j & 7);
      *(bf16x8*)(dst + c * 8) = w;
    }
  }
  {
    const int jr = t >> 2;
    const int d0 = (t & 3) * 16;
    const float* vsrc = V + ibase + (size_t)(j0 + jr) * HD + d0;
#pragma unroll
    for (int h = 0; h < 4; ++h) {
      float4 a = *(const float4*)(vsrc + 4 * h);
      sT[(d0 + 4 * h + 0) * 72 + jr] = __builtin_bit_cast(unsigned short, (__bf16)a.x);
      sT[(d0 + 4 * h + 1) * 72 + jr] = __builtin_bit_cast(unsigned short, (__bf16)a.y);
      sT[(d0 + 4 * h + 2) * 72 + jr] = __builtin_bit_cast(unsigned short, (__bf16)a.z);
      sT[(d0 + 4 * h + 3) * 72 + jr] = __builtin_bit_cast(unsigned short, (__bf16)a.w);
    }
  }
  __syncthreads();
  {
#pragma unroll
    for (int p = 0; p < 2; ++p) {
      const int cid = t + 256 * p;
      const int d = cid >> 3;
      const int jj = cid & 7;
      bf16x8 w = *(const bf16x8*)(&sT[d * 72 + 8 * jj]);
      const int c = jj ^ (d & 7);
      *(bf16x8*)(Vt + (size_t)bh * HD * SEQ + (size_t)d * SEQ + j0 + c * 8) = w;
    }
  }
}

// ---------------------------------------------------------------------------
// Main: paired-q swapped-operand 32x32 MFMA flash attention.
// Block = 4 waves, handles q-tiles qbA=p (low) and qbB=NQB-1-p (high).
// Wave w owns rows [qb*128+32w, +32) of each tile. KV tiles of 64, 3-buffer
// depth-2 prefetch with counted vmcnt.
// ---------------------------------------------------------------------------
__global__ __launch_bounds__(256, 2) void fattn_kernel(
    const float* __restrict__ Q, const unsigned short* __restrict__ Kswz,
    const unsigned short* __restrict__ Vt, float* __restrict__ O) {
  __shared__ __align__(16) unsigned short sbuf[3][2 * 64 * 64];  // K | V^T

  const int tid = threadIdx.x;
  const int wid = tid >> 6;
  const int lane = tid & 63;
  const int l31 = lane & 31;
  const int hi = lane >> 5;

  const int p = blockIdx.x;       // 0..NQB/2-1 (heaviest stager first)
  const int qbA = p;              // low q-tile
  const int qbB = NQB - 1 - p;    // high q-tile
  const int bh = blockIdx.y;

  const int i0A = qbA * 128 + wid * 32;  // wave's first q row, low
  const int i0B = qbB * 128 + wid * 32;  // high
  const int igA = i0A + l31;
  const int igB = i0B + l31;

  const float* Qp = Q + (size_t)bh * SEQ * HD;
  const unsigned short* Kg = Kswz + (size_t)bh * SEQ * HD;
  const unsigned short* Vg = Vt + (size_t)bh * HD * SEQ;
  float* Op = O + (size_t)bh * SEQ * HD;

  // ---- Q fragments (B-operand layout), scale*log2e folded ----
  const float qscale = 0.125f * 1.44269504088896340736f;
  bf16x8 qfA[4], qfB[4];
#pragma unroll
  for (int grp = 0; grp < 2; ++grp) {
    const float* qr = Qp + (size_t)(grp ? igB : igA) * HD + 8 * hi;
#pragma unroll
    for (int c = 0; c < 4; ++c) {
      float4 a = *(const float4*)(qr + 16 * c);
      float4 b = *(const float4*)(qr + 16 * c + 4);
      bf16x8 w;
      w[0] = (__bf16)(a.x * qscale); w[1] = (__bf16)(a.y * qscale);
      w[2] = (__bf16)(a.z * qscale); w[3] = (__bf16)(a.w * qscale);
      w[4] = (__bf16)(b.x * qscale); w[5] = (__bf16)(b.y * qscale);
      w[6] = (__bf16)(b.z * qscale); w[7] = (__bf16)(b.w * qscale);
      if (grp) qfB[c] = w; else qfA[c] = w;
    }
  }

  f32x16 oAl, oBl, oAh, oBh;
#pragma unroll
  for (int r = 0; r < 16; ++r) { oAl[r] = 0.f; oBl[r] = 0.f; oAh[r] = 0.f; oBh[r] = 0.f; }
  float mA = -1e30f, lA = 0.f, mB = -1e30f, lB = 0.f;

  const int nkb = 2 * qbB + 2;       // tiles needed by the high q-tile
  const int kbLowMax = 2 * qbA + 1;  // last tile the low q-tile needs

  auto stage = [&](int buf, int j0s) {
    unsigned short* bK = &sbuf[buf][0];
    unsigned short* bV = &sbuf[buf][4096];
#pragma unroll
    for (int tt = 0; tt < 2; ++tt) {
      const int row = 16 * wid + 8 * tt;  // uniform per wave
      const unsigned short* gk =
          Kg + (size_t)(j0s + row + (lane >> 3)) * HD + (lane & 7) * 8;
      gload_lds16(gk, bK + row * HD);
      const unsigned short* gv =
          Vg + (size_t)(row + (lane >> 3)) * SEQ + j0s + (lane & 7) * 8;
      gload_lds16(gv, bV + row * HD);
    }
  };

  const int swz = (l31 & 7) << 4;

  stage(0, 0);
  stage(1, 64);

  for (int kb = 0; kb < nkb; ++kb) {
    const int j0 = kb * 64;
    // counted drain: tile kb's 4 loads done; next tile's stay in flight
    if (kb + 1 < nkb) {
      asm volatile("s_waitcnt vmcnt(4)" ::: "memory");
    } else {
      asm volatile("s_waitcnt vmcnt(0)" ::: "memory");
    }
    __builtin_amdgcn_s_barrier();
    __builtin_amdgcn_sched_barrier(0);
    if (kb + 2 < nkb) stage((kb + 2) % 3, j0 + 128);

    const unsigned short* bK = &sbuf[kb % 3][0];
    const unsigned short* bV = &sbuf[kb % 3][4096];
    const bool lowAct = (kb <= kbLowMax);

    // ---- QK^T (swapped): kf reads shared across both q-groups ----
    f32x16 sAl, sBl, sAh, sBh;
#pragma unroll
    for (int r = 0; r < 16; ++r) { sAl[r] = 0.f; sBl[r] = 0.f; sAh[r] = 0.f; sBh[r] = 0.f; }

    __builtin_amdgcn_s_setprio(1);
    if (lowAct) {
#pragma unroll
      for (int c = 0; c < 4; ++c) {
        const int boff = (32 * c + 16 * hi) ^ swz;
        bf16x8 kf0 = *(const bf16x8*)((const char*)bK + l31 * 128 + boff);
        bf16x8 kf1 = *(const bf16x8*)((const char*)bK + (32 + l31) * 128 + boff);
        sAh = __builtin_amdgcn_mfma_f32_32x32x16_bf16(kf0, qfB[c], sAh, 0, 0, 0);
        sBh = __builtin_amdgcn_mfma_f32_32x32x16_bf16(kf1, qfB[c], sBh, 0, 0, 0);
        sAl = __builtin_amdgcn_mfma_f32_32x32x16_bf16(kf0, qfA[c], sAl, 0, 0, 0);
        sBl = __builtin_amdgcn_mfma_f32_32x32x16_bf16(kf1, qfA[c], sBl, 0, 0, 0);
      }
    } else {
#pragma unroll
      for (int c = 0; c < 4; ++c) {
        const int boff = (32 * c + 16 * hi) ^ swz;
        bf16x8 kf0 = *(const bf16x8*)((const char*)bK + l31 * 128 + boff);
        bf16x8 kf1 = *(const bf16x8*)((const char*)bK + (32 + l31) * 128 + boff);
        sAh = __builtin_amdgcn_mfma_f32_32x32x16_bf16(kf0, qfB[c], sAh, 0, 0, 0);
        sBh = __builtin_amdgcn_mfma_f32_32x32x16_bf16(kf1, qfB[c], sBh, 0, 0, 0);
      }
    }
    __builtin_amdgcn_s_setprio(0);

    // ---- causal masks (diagonal tiles only; wave-uniform tests) ----
    if (j0 + 63 > i0B) {
#pragma unroll
      for (int r = 0; r < 16; ++r) {
        const int jl = j0 + (r & 3) + 8 * (r >> 2) + 4 * hi;
        sAh[r] = (jl <= igB) ? sAh[r] : -1e30f;
        sBh[r] = (jl + 32 <= igB) ? sBh[r] : -1e30f;
      }
    }
    if (lowAct && (j0 + 63 > i0A)) {
#pragma unroll
      for (int r = 0; r < 16; ++r) {
        const int jl = j0 + (r & 3) + 8 * (r >> 2) + 4 * hi;
        sAl[r] = (jl <= igA) ? sAl[r] : -1e30f;
        sBl[r] = (jl + 32 <= igA) ? sBl[r] : -1e30f;
      }
    }

    // ---- softmax + PV-fragment build, per group ----
    bf16x8 pfh[4], pfl[4];

#define SOFTMAX_FRAG(SA, SB, MRUN, LRUN, OA, OB, PFR)                        \
    {                                                                        \
      float pmax = fmaxf(tmax16(SA), tmax16(SB));                            \
      pmax = fmaxf(pmax, __shfl_xor(pmax, 32));                              \
      if (!__all(pmax - MRUN <= 10.0f)) {                                    \
        const float mn = fmaxf(MRUN, pmax);                                  \
        const float al = __builtin_amdgcn_exp2f(MRUN - mn);                  \
        MRUN = mn;                                                           \
        LRUN *= al;                                                          \
        _Pragma("unroll")                                                    \
        for (int r = 0; r < 16; ++r) { OA[r] *= al; OB[r] *= al; }           \
      }                                                                      \
      float rs0 = 0.f, rs1 = 0.f, rs2 = 0.f, rs3 = 0.f;                      \
      _Pragma("unroll")                                                      \
      for (int r = 0; r < 4; ++r) {                                          \
        SA[4 * r + 0] = __builtin_amdgcn_exp2f(SA[4 * r + 0] - MRUN);        \
        SA[4 * r + 1] = __builtin_amdgcn_exp2f(SA[4 * r + 1] - MRUN);        \
        SA[4 * r + 2] = __builtin_amdgcn_exp2f(SA[4 * r + 2] - MRUN);        \
        SA[4 * r + 3] = __builtin_amdgcn_exp2f(SA[4 * r + 3] - MRUN);        \
        rs0 += SA[4 * r + 0]; rs1 += SA[4 * r + 1];                          \
        rs2 += SA[4 * r + 2]; rs3 += SA[4 * r + 3];                          \
      }                                                                      \
      _Pragma("unroll")                                                      \
      for (int r = 0; r < 4; ++r) {                                          \
        SB[4 * r + 0] = __builtin_amdgcn_exp2f(SB[4 * r + 0] - MRUN);        \
        SB[4 * r + 1] = __builtin_amdgcn_exp2f(SB[4 * r + 1] - MRUN);        \
        SB[4 * r + 2] = __builtin_amdgcn_exp2f(SB[4 * r + 2] - MRUN);        \
        SB[4 * r + 3] = __builtin_amdgcn_exp2f(SB[4 * r + 3] - MRUN);        \
        rs0 += SB[4 * r + 0]; rs1 += SB[4 * r + 1];                          \
        rs2 += SB[4 * r + 2]; rs3 += SB[4 * r + 3];                          \
      }                                                                      \
      float rs = (rs0 + rs1) + (rs2 + rs3);                                  \
      rs += __shfl_xor(rs, 32);                                              \
      LRUN += rs;                                                            \
      MKFRAG(SA, 0, PFR[0]) MKFRAG(SA, 8, PFR[1])                            \
      MKFRAG(SB, 0, PFR[2]) MKFRAG(SB, 8, PFR[3])                            \
    }

#define MKFRAG(SV, BASE, DST)                                                \
    {                                                                        \
      unsigned a0 = cvtpk_bf16(SV[BASE + 0], SV[BASE + 1]);                  \
      unsigned b0 = cvtpk_bf16(SV[BASE + 4], SV[BASE + 5]);                  \
      asm("v_permlane32_swap_b32 %0, %1" : "+v"(a0), "+v"(b0));              \
      unsigned a1 = cvtpk_bf16(SV[BASE + 2], SV[BASE + 3]);                  \
      unsigned b1 = cvtpk_bf16(SV[BASE + 6], SV[BASE + 7]);                  \
      asm("v_permlane32_swap_b32 %0, %1" : "+v"(a1), "+v"(b1));              \
      u32x4 wv = {a0, a1, b0, b1};                                           \
      DST = __builtin_bit_cast(bf16x8, wv);                                  \
    }

    SOFTMAX_FRAG(sAh, sBh, mB, lB, oAh, oBh, pfh)
    if (lowAct) {
      SOFTMAX_FRAG(sAl, sBl, mA, lA, oAl, oBl, pfl)
    }
#undef SOFTMAX_FRAG
#undef MKFRAG

    // ---- PV: vf reads shared across both q-groups ----
    __builtin_amdgcn_s_setprio(1);
    if (lowAct) {
#pragma unroll
      for (int ks = 0; ks < 4; ++ks) {
        const int vbo = (32 * ks + 16 * hi) ^ swz;
        bf16x8 vf0 = *(const bf16x8*)((const char*)bV + l31 * 128 + vbo);
        bf16x8 vf1 = *(const bf16x8*)((const char*)bV + (32 + l31) * 128 + vbo);
        oAh = __builtin_amdgcn_mfma_f32_32x32x16_bf16(vf0, pfh[ks], oAh, 0, 0, 0);
        oBh = __builtin_amdgcn_mfma_f32_32x32x16_bf16(vf1, pfh[ks], oBh, 0, 0, 0);
        oAl = __builtin_amdgcn_mfma_f32_32x32x16_bf16(vf0, pfl[ks], oAl, 0, 0, 0);
        oBl = __builtin_amdgcn_mfma_f32_32x32x16_bf16(vf1, pfl[ks], oBl, 0, 0, 0);
      }
    } else {
#pragma unroll
      for (int ks = 0; ks < 4; ++ks) {
        const int vbo = (32 * ks + 16 * hi) ^ swz;
        bf16x8 vf0 = *(const bf16x8*)((const char*)bV + l31 * 128 + vbo);
        bf16x8 vf1 = *(const bf16x8*)((const char*)bV + (32 + l31) * 128 + vbo);
        oAh = __builtin_amdgcn_mfma_f32_32x32x16_bf16(vf0, pfh[ks], oAh, 0, 0, 0);
        oBh = __builtin_amdgcn_mfma_f32_32x32x16_bf16(vf1, pfh[ks], oBh, 0, 0, 0);
      }
    }
    __builtin_amdgcn_s_setprio(0);
  }

  // ---- epilogue: both q-groups; lane owns one row, d = crow(r,hi)+32dt ----
#pragma unroll
  for (int grp = 0; grp < 2; ++grp) {
    const float inv = 1.f / (grp ? lB : lA);
    float* orow = Op + (size_t)(grp ? igB : igA) * HD;
    const f32x16& xA = grp ? oAh : oAl;
    const f32x16& xB = grp ? oBh : oBl;
#pragma unroll
    for (int q2 = 0; q2 < 4; ++q2) {
      float4 o;
      o.x = xA[4 * q2 + 0] * inv; o.y = xA[4 * q2 + 1] * inv;
      o.z = xA[4 * q2 + 2] * inv; o.w = xA[4 * q2 + 3] * inv;
      *(float4*)(orow + 8 * q2 + 4 * hi) = o;
      float4 pq;
      pq.x = xB[4 * q2 + 0] * inv; pq.y = xB[4 * q2 + 1] * inv;
      pq.z = xB[4 * q2 + 2] * inv; pq.w = xB[4 * q2 + 3] * inv;
      *(float4*)(orow + 32 + 8 * q2 + 4 * hi) = pq;
    }
  }
}

// ---------------------------------------------------------------------------
// Fallback (verified round-1 kernel) in case ws_size is too small.
// ---------------------------------------------------------------------------
__global__ void fattn_fallback(const float* __restrict__ Q,
                               const float* __restrict__ K,
                               const float* __restrict__ V,
                               float* __restrict__ O) {
  __shared__ __align__(16) unsigned short sK[64 * 64];
  __shared__ __align__(16) unsigned short sVt[64 * 72];
  __shared__ __align__(16) unsigned short sP[4][16 * 72];

  const int tid = threadIdx.x;
  const int wid = tid >> 6;
  const int lane = tid & 63;
  const int g = lane >> 4;
  const int lx = lane & 15;

  const int qb = (int)gridDim.x - 1 - (int)blockIdx.x;
  const int bh = blockIdx.y;
  const int q0 = qb * 64;

  const size_t base = (size_t)bh * SEQ * HD;
  const float* Qp = Q + base;
  const float* Kp = K + base;
  const float* Vp = V + base;
  float* Op = O + base;

  bf16x8 qf[2];
  {
    const int row = q0 + wid * 16 + lx;
    const float* qr = Qp + (size_t)row * HD + 8 * g;
#pragma unroll
    for (int c = 0; c < 2; ++c) {
      float4 a = *(const float4*)(qr + 32 * c);
      float4 b = *(const float4*)(qr + 32 * c + 4);
      bf16x8 w;
      w[0] = (__bf16)(a.x * 0.125f); w[1] = (__bf16)(a.y * 0.125f);
      w[2] = (__bf16)(a.z * 0.125f); w[3] = (__bf16)(a.w * 0.125f);
      w[4] = (__bf16)(b.x * 0.125f); w[5] = (__bf16)(b.y * 0.125f);
      w[6] = (__bf16)(b.z * 0.125f); w[7] = (__bf16)(b.w * 0.125f);
      qf[c] = w;
    }
  }

  f32x4 acc[4];
#pragma unroll
  for (int dt = 0; dt < 4; ++dt) acc[dt] = (f32x4){0.f, 0.f, 0.f, 0.f};
  float m_run[4], l_run[4];
#pragma unroll
  for (int r = 0; r < 4; ++r) { m_run[r] = -1e30f; l_run[r] = 0.f; }

  const int iw0 = q0 + wid * 16;
  const int nkb = qb + 1;

  for (int kb = 0; kb < nkb; ++kb) {
    const int j0 = kb * 64;
    __syncthreads();
    {
      const int jr = tid >> 2;
      const int d0 = (tid & 3) * 16;
      const float* src = Kp + (size_t)(j0 + jr) * HD + d0;
#pragma unroll
      for (int h = 0; h < 2; ++h) {
        bf16x8 w = cvt8(src + 8 * h);
        const int byteoff = ((d0 + 8 * h) * 2) ^ ((jr & 7) << 4);
        *(bf16x8*)((char*)sK + jr * 128 + byteoff) = w;
      }
      const float* vsrc = Vp + (size_t)(j0 + jr) * HD + d0;
#pragma unroll
      for (int h = 0; h < 4; ++h) {
        float4 a = *(const float4*)(vsrc + 4 * h);
        sVt[(d0 + 4 * h + 0) * 72 + jr] = __builtin_bit_cast(unsigned short, (__bf16)a.x);
        sVt[(d0 + 4 * h + 1) * 72 + jr] = __builtin_bit_cast(unsigned short, (__bf16)a.y);
        sVt[(d0 + 4 * h + 2) * 72 + jr] = __builtin_bit_cast(unsigned short, (__bf16)a.z);
        sVt[(d0 + 4 * h + 3) * 72 + jr] = __builtin_bit_cast(unsigned short, (__bf16)a.w);
      }
    }
    __syncthreads();

    float s[4][4];
#pragma unroll
    for (int jt = 0; jt < 4; ++jt) {
      f32x4 c = (f32x4){0.f, 0.f, 0.f, 0.f};
#pragma unroll
      for (int cc = 0; cc < 2; ++cc) {
        const int row = jt * 16 + lx;
        const int byteoff = (16 * g + 64 * cc) ^ ((row & 7) << 4);
        bf16x8 kf = *(const bf16x8*)((const char*)sK + row * 128 + byteoff);
        c = __builtin_amdgcn_mfma_f32_16x16x32_bf16(qf[cc], kf, c, 0, 0, 0);
      }
      const int jg = j0 + jt * 16 + lx;
#pragma unroll
      for (int r = 0; r < 4; ++r) {
        const int igf = iw0 + 4 * g + r;
        s[jt][r] = (jg <= igf) ? c[r] : -1e30f;
      }
    }

#pragma unroll
    for (int r = 0; r < 4; ++r) {
      float mt = fmaxf(fmaxf(s[0][r], s[1][r]), fmaxf(s[2][r], s[3][r]));
#pragma unroll
      for (int msk = 1; msk <= 8; msk <<= 1) mt = fmaxf(mt, __shfl_xor(mt, msk));
      const float mn = fmaxf(m_run[r], mt);
      const float alpha = __expf(m_run[r] - mn);
      m_run[r] = mn;
      float rs = 0.f;
#pragma unroll
      for (int jt = 0; jt < 4; ++jt) {
        const float pv = __expf(s[jt][r] - mn);
        s[jt][r] = pv;
        rs += pv;
      }
#pragma unroll
      for (int msk = 1; msk <= 8; msk <<= 1) rs += __shfl_xor(rs, msk);
      l_run[r] = l_run[r] * alpha + rs;
#pragma unroll
      for (int dt = 0; dt < 4; ++dt) acc[dt][r] *= alpha;
    }

#pragma unroll
    for (int jt = 0; jt < 4; ++jt)
#pragma unroll
      for (int r = 0; r < 4; ++r)
        sP[wid][(4 * g + r) * 72 + jt * 16 + lx] =
            __builtin_bit_cast(unsigned short, (__bf16)s[jt][r]);
    asm volatile("s_waitcnt lgkmcnt(0)" ::: "memory");

#pragma unroll
    for (int cc = 0; cc < 2; ++cc) {
      bf16x8 pf = *(const bf16x8*)(&sP[wid][lx * 72 + 8 * g + 32 * cc]);
#pragma unroll
      for (int dt = 0; dt < 4; ++dt) {
        bf16x8 vf = *(const bf16x8*)(&sVt[(lx + 16 * dt) * 72 + 8 * g + 32 * cc]);
        acc[dt] = __builtin_amdgcn_mfma_f32_16x16x32_bf16(pf, vf, acc[dt], 0, 0, 0);
      }
    }
  }

#pragma unroll
  for (int r = 0; r < 4; ++r) {
    const float inv = 1.f / l_run[r];
    const int igf = q0 + wid * 16 + 4 * g + r;
    float* orow = Op + (size_t)igf * HD + lx;
#pragma unroll
    for (int dt = 0; dt < 4; ++dt) orow[16 * dt] = acc[dt][r] * inv;
  }
}

extern "C" void kernel_launch(void* const* d_in, const int* in_sizes, int n_in,
                              void* d_out, int out_size, void* d_ws, size_t ws_size,
                              hipStream_t stream) {
  const float* q = (const float*)d_in[0];
  const float* k = (const float*)d_in[1];
  const float* v = (const float*)d_in[2];
  float* o = (float*)d_out;

  const size_t kv_elems = (size_t)64 * SEQ * HD;
  const size_t need = 2 * kv_elems * sizeof(unsigned short);  // 32 MiB

  if (ws_size >= need) {
    unsigned short* kswz = (unsigned short*)d_ws;
    unsigned short* vt = kswz + kv_elems;
    dim3 pgrid(SEQ / 64, 64);
    prep_kernel<<<pgrid, 256, 0, stream>>>(k, v, kswz, vt);
    dim3 grid(NQB / 2, 64);  // paired q-tiles: uniform work
    fattn_kernel<<<grid, 256, 0, stream>>>(q, kswz, vt, o);
  } else {
    dim3 grid(SEQ / 64, 64);
    fattn_fallback<<<grid, 256, 0, stream>>>(q, k, v, o);
  }
}

// Round 7
// 88.885 us; speedup vs baseline: 3.1306x; 1.0045x over previous
//
#include <hip/hip_runtime.h>
#include <hip/hip_bf16.h>

#define SEQ 2048
#define HD 64
#define NQB (SEQ / 128)  // 16 q-tiles of 128 rows

typedef __bf16 bf16x8 __attribute__((ext_vector_type(8)));
typedef float f32x4 __attribute__((ext_vector_type(4)));
typedef float f32x16 __attribute__((ext_vector_type(16)));
typedef unsigned int u32x4 __attribute__((ext_vector_type(4)));

typedef const __attribute__((address_space(1))) void gvoid_t;
typedef __attribute__((address_space(3))) void svoid_t;

__device__ __forceinline__ void gload_lds16(const void* g, void* l) {
  __builtin_amdgcn_global_load_lds((gvoid_t*)g, (svoid_t*)l, 16, 0, 0);
}

__device__ __forceinline__ bf16x8 cvt8(const float* p) {
  float4 a = *(const float4*)p;
  float4 b = *(const float4*)(p + 4);
  bf16x8 w;
  w[0] = (__bf16)a.x; w[1] = (__bf16)a.y; w[2] = (__bf16)a.z; w[3] = (__bf16)a.w;
  w[4] = (__bf16)b.x; w[5] = (__bf16)b.y; w[6] = (__bf16)b.z; w[7] = (__bf16)b.w;
  return w;
}

__device__ __forceinline__ unsigned cvtpk_bf16(float lo, float hi) {
  unsigned r;
  asm("v_cvt_pk_bf16_f32 %0, %1, %2" : "=v"(r) : "v"(lo), "v"(hi));
  return r;
}

// pairwise-tree max over an f32x16 (short dep chains) -- R4-verified
__device__ __forceinline__ float tmax16(const f32x16& v) {
  float a0 = fmaxf(v[0], v[1]), a1 = fmaxf(v[2], v[3]);
  float a2 = fmaxf(v[4], v[5]), a3 = fmaxf(v[6], v[7]);
  float a4 = fmaxf(v[8], v[9]), a5 = fmaxf(v[10], v[11]);
  float a6 = fmaxf(v[12], v[13]), a7 = fmaxf(v[14], v[15]);
  float b0 = fmaxf(a0, a1), b1 = fmaxf(a2, a3), b2 = fmaxf(a4, a5), b3 = fmaxf(a6, a7);
  return fmaxf(fmaxf(b0, b1), fmaxf(b2, b3));
}

// ---------------------------------------------------------------------------
// Pre-pass (verified R2-R4): K -> bf16 swizzled rows; V -> V^T bf16
// [bh][d][SEQ] with per-64-j-segment swizzle keyed on (d&7).
// ---------------------------------------------------------------------------
__global__ void prep_kernel(const float* __restrict__ K,
                            const float* __restrict__ V,
                            unsigned short* __restrict__ Kswz,
                            unsigned short* __restrict__ Vt) {
  __shared__ __align__(16) unsigned short sT[64 * 72];
  const int t = threadIdx.x;
  const int kb = blockIdx.x;
  const int bh = blockIdx.y;
  const int j0 = kb * 64;
  const size_t ibase = (size_t)bh * SEQ * HD;

  {
    const int j = t >> 2;
    const int m = (t & 3) * 2;
    const float* src = K + ibase + (size_t)(j0 + j) * HD + m * 8;
    unsigned short* dst = Kswz + ibase + (size_t)(j0 + j) * HD;
#pragma unroll
    for (int h = 0; h < 2; ++h) {
      bf16x8 w = cvt8(src + 8 * h);
      const int c = (m + h) ^ (j & 7);
      *(bf16x8*)(dst + c * 8) = w;
    }
  }
  {
    const int jr = t >> 2;
    const int d0 = (t & 3) * 16;
    const float* vsrc = V + ibase + (size_t)(j0 + jr) * HD + d0;
#pragma unroll
    for (int h = 0; h < 4; ++h) {
      float4 a = *(const float4*)(vsrc + 4 * h);
      sT[(d0 + 4 * h + 0) * 72 + jr] = __builtin_bit_cast(unsigned short, (__bf16)a.x);
      sT[(d0 + 4 * h + 1) * 72 + jr] = __builtin_bit_cast(unsigned short, (__bf16)a.y);
      sT[(d0 + 4 * h + 2) * 72 + jr] = __builtin_bit_cast(unsigned short, (__bf16)a.z);
      sT[(d0 + 4 * h + 3) * 72 + jr] = __builtin_bit_cast(unsigned short, (__bf16)a.w);
    }
  }
  __syncthreads();
  {
#pragma unroll
    for (int p = 0; p < 2; ++p) {
      const int cid = t + 256 * p;
      const int d = cid >> 3;
      const int jj = cid & 7;
      bf16x8 w = *(const bf16x8*)(&sT[d * 72 + 8 * jj]);
      const int c = jj ^ (d & 7);
      *(bf16x8*)(Vt + (size_t)bh * HD * SEQ + (size_t)d * SEQ + j0 + c * 8) = w;
    }
  }
}

// ---------------------------------------------------------------------------
// Main: paired-q swapped-operand 32x32 MFMA flash attention (R4 structure,
// verified). Block = 4 waves, q-tiles qbA=p and qbB=NQB-1-p; KV tiles of 64,
// 3-buffer ring, depth-2 prefetch with counted vmcnt(4).
// Single R7 change vs R4: first QK MFMA consumes persistent z16 zero vector
// (peeled c=0) instead of 64 per-tile v_mov zero-inits.
// ---------------------------------------------------------------------------
__global__ __launch_bounds__(256, 2) void fattn_kernel(
    const float* __restrict__ Q, const unsigned short* __restrict__ Kswz,
    const unsigned short* __restrict__ Vt, float* __restrict__ O) {
  __shared__ __align__(16) unsigned short sbuf[3][2 * 64 * 64];  // K | V^T

  const int tid = threadIdx.x;
  const int wid = tid >> 6;
  const int lane = tid & 63;
  const int l31 = lane & 31;
  const int hi = lane >> 5;

  const int p = blockIdx.x;     // 0..NQB/2-1
  const int qbA = p;            // low q-tile
  const int qbB = NQB - 1 - p;  // high q-tile
  const int bh = blockIdx.y;

  const int i0A = qbA * 128 + wid * 32;
  const int i0B = qbB * 128 + wid * 32;
  const int igA = i0A + l31;
  const int igB = i0B + l31;

  const float* Qp = Q + (size_t)bh * SEQ * HD;
  const unsigned short* Kg = Kswz + (size_t)bh * SEQ * HD;
  const unsigned short* Vg = Vt + (size_t)bh * HD * SEQ;
  float* Op = O + (size_t)bh * SEQ * HD;

  // ---- Q fragments (B-operand layout), scale*log2e folded ----
  const float qscale = 0.125f * 1.44269504088896340736f;
  bf16x8 qfA[4], qfB[4];
#pragma unroll
  for (int grp = 0; grp < 2; ++grp) {
    const float* qr = Qp + (size_t)(grp ? igB : igA) * HD + 8 * hi;
#pragma unroll
    for (int c = 0; c < 4; ++c) {
      float4 a = *(const float4*)(qr + 16 * c);
      float4 b = *(const float4*)(qr + 16 * c + 4);
      bf16x8 w;
      w[0] = (__bf16)(a.x * qscale); w[1] = (__bf16)(a.y * qscale);
      w[2] = (__bf16)(a.z * qscale); w[3] = (__bf16)(a.w * qscale);
      w[4] = (__bf16)(b.x * qscale); w[5] = (__bf16)(b.y * qscale);
      w[6] = (__bf16)(b.z * qscale); w[7] = (__bf16)(b.w * qscale);
      if (grp) qfB[c] = w; else qfA[c] = w;
    }
  }

  // persistent zero C-operand (R7 change)
  f32x16 z16;
#pragma unroll
  for (int r = 0; r < 16; ++r) z16[r] = 0.f;

  f32x16 oAl, oBl, oAh, oBh;
#pragma unroll
  for (int r = 0; r < 16; ++r) { oAl[r] = 0.f; oBl[r] = 0.f; oAh[r] = 0.f; oBh[r] = 0.f; }
  float mA = -1e30f, lA = 0.f, mB = -1e30f, lB = 0.f;

  const int nkb = 2 * qbB + 2;       // tiles needed by the high q-tile
  const int kbLowMax = 2 * qbA + 1;  // last tile the low q-tile needs

  auto stage = [&](int buf, int j0s) {
    unsigned short* bK = &sbuf[buf][0];
    unsigned short* bV = &sbuf[buf][4096];
#pragma unroll
    for (int tt = 0; tt < 2; ++tt) {
      const int row = 16 * wid + 8 * tt;  // uniform per wave
      const unsigned short* gk =
          Kg + (size_t)(j0s + row + (lane >> 3)) * HD + (lane & 7) * 8;
      gload_lds16(gk, bK + row * HD);
      const unsigned short* gv =
          Vg + (size_t)(row + (lane >> 3)) * SEQ + j0s + (lane & 7) * 8;
      gload_lds16(gv, bV + row * HD);
    }
  };

  const int swz = (l31 & 7) << 4;

  stage(0, 0);
  stage(1, 64);

  for (int kb = 0; kb < nkb; ++kb) {
    const int j0 = kb * 64;
    // counted drain: tile kb's 4 loads done; next tile's stay in flight
    if (kb + 1 < nkb) {
      asm volatile("s_waitcnt vmcnt(4)" ::: "memory");
    } else {
      asm volatile("s_waitcnt vmcnt(0)" ::: "memory");
    }
    __builtin_amdgcn_s_barrier();
    __builtin_amdgcn_sched_barrier(0);
    if (kb + 2 < nkb) stage((kb + 2) % 3, j0 + 128);

    const unsigned short* bK = &sbuf[kb % 3][0];
    const unsigned short* bV = &sbuf[kb % 3][4096];
    const bool lowAct = (kb <= kbLowMax);

    // ---- QK^T (swapped): kf reads shared across both q-groups ----
    f32x16 sAl, sBl, sAh, sBh;

    __builtin_amdgcn_s_setprio(1);
    {  // c = 0 peeled: C-operand = persistent z16
      const int boff = (16 * hi) ^ swz;
      bf16x8 kf0 = *(const bf16x8*)((const char*)bK + l31 * 128 + boff);
      bf16x8 kf1 = *(const bf16x8*)((const char*)bK + (32 + l31) * 128 + boff);
      sAh = __builtin_amdgcn_mfma_f32_32x32x16_bf16(kf0, qfB[0], z16, 0, 0, 0);
      sBh = __builtin_amdgcn_mfma_f32_32x32x16_bf16(kf1, qfB[0], z16, 0, 0, 0);
      if (lowAct) {
        sAl = __builtin_amdgcn_mfma_f32_32x32x16_bf16(kf0, qfA[0], z16, 0, 0, 0);
        sBl = __builtin_amdgcn_mfma_f32_32x32x16_bf16(kf1, qfA[0], z16, 0, 0, 0);
      } else {
        sAl = z16; sBl = z16;  // keep defined (never consumed when !lowAct)
      }
    }
#pragma unroll
    for (int c = 1; c < 4; ++c) {
      const int boff = (32 * c + 16 * hi) ^ swz;
      bf16x8 kf0 = *(const bf16x8*)((const char*)bK + l31 * 128 + boff);
      bf16x8 kf1 = *(const bf16x8*)((const char*)bK + (32 + l31) * 128 + boff);
      sAh = __builtin_amdgcn_mfma_f32_32x32x16_bf16(kf0, qfB[c], sAh, 0, 0, 0);
      sBh = __builtin_amdgcn_mfma_f32_32x32x16_bf16(kf1, qfB[c], sBh, 0, 0, 0);
      if (lowAct) {
        sAl = __builtin_amdgcn_mfma_f32_32x32x16_bf16(kf0, qfA[c], sAl, 0, 0, 0);
        sBl = __builtin_amdgcn_mfma_f32_32x32x16_bf16(kf1, qfA[c], sBl, 0, 0, 0);
      }
    }
    __builtin_amdgcn_s_setprio(0);

    // ---- causal masks (diagonal tiles only; wave-uniform tests) ----
    if (j0 + 63 > i0B) {
#pragma unroll
      for (int r = 0; r < 16; ++r) {
        const int jl = j0 + (r & 3) + 8 * (r >> 2) + 4 * hi;
        sAh[r] = (jl <= igB) ? sAh[r] : -1e30f;
        sBh[r] = (jl + 32 <= igB) ? sBh[r] : -1e30f;
      }
    }
    if (lowAct && (j0 + 63 > i0A)) {
#pragma unroll
      for (int r = 0; r < 16; ++r) {
        const int jl = j0 + (r & 3) + 8 * (r >> 2) + 4 * hi;
        sAl[r] = (jl <= igA) ? sAl[r] : -1e30f;
        sBl[r] = (jl + 32 <= igA) ? sBl[r] : -1e30f;
      }
    }

    // ---- softmax + PV-fragment build, per group (R4-verified reductions) ----
    bf16x8 pfh[4], pfl[4];

#define MKFRAG(SV, BASE, DST)                                                \
    {                                                                        \
      unsigned a0 = cvtpk_bf16(SV[BASE + 0], SV[BASE + 1]);                  \
      unsigned b0 = cvtpk_bf16(SV[BASE + 4], SV[BASE + 5]);                  \
      asm("v_permlane32_swap_b32 %0, %1" : "+v"(a0), "+v"(b0));              \
      unsigned a1 = cvtpk_bf16(SV[BASE + 2], SV[BASE + 3]);                  \
      unsigned b1 = cvtpk_bf16(SV[BASE + 6], SV[BASE + 7]);                  \
      asm("v_permlane32_swap_b32 %0, %1" : "+v"(a1), "+v"(b1));              \
      u32x4 wv = {a0, a1, b0, b1};                                           \
      DST = __builtin_bit_cast(bf16x8, wv);                                  \
    }

#define SOFTMAX_FRAG(SA, SB, MRUN, LRUN, OA, OB, PFR)                        \
    {                                                                        \
      float pmax = fmaxf(tmax16(SA), tmax16(SB));                            \
      pmax = fmaxf(pmax, __shfl_xor(pmax, 32));                              \
      if (!__all(pmax - MRUN <= 10.0f)) {                                    \
        const float mn = fmaxf(MRUN, pmax);                                  \
        const float al = __builtin_amdgcn_exp2f(MRUN - mn);                  \
        MRUN = mn;                                                           \
        LRUN *= al;                                                          \
        _Pragma("unroll")                                                    \
        for (int r = 0; r < 16; ++r) { OA[r] *= al; OB[r] *= al; }           \
      }                                                                      \
      float rs0 = 0.f, rs1 = 0.f, rs2 = 0.f, rs3 = 0.f;                      \
      _Pragma("unroll")                                                      \
      for (int r = 0; r < 4; ++r) {                                          \
        SA[4 * r + 0] = __builtin_amdgcn_exp2f(SA[4 * r + 0] - MRUN);        \
        SA[4 * r + 1] = __builtin_amdgcn_exp2f(SA[4 * r + 1] - MRUN);        \
        SA[4 * r + 2] = __builtin_amdgcn_exp2f(SA[4 * r + 2] - MRUN);        \
        SA[4 * r + 3] = __builtin_amdgcn_exp2f(SA[4 * r + 3] - MRUN);        \
        rs0 += SA[4 * r + 0]; rs1 += SA[4 * r + 1];                          \
        rs2 += SA[4 * r + 2]; rs3 += SA[4 * r + 3];                          \
      }                                                                      \
      _Pragma("unroll")                                                      \
      for (int r = 0; r < 4; ++r) {                                          \
        SB[4 * r + 0] = __builtin_amdgcn_exp2f(SB[4 * r + 0] - MRUN);        \
        SB[4 * r + 1] = __builtin_amdgcn_exp2f(SB[4 * r + 1] - MRUN);        \
        SB[4 * r + 2] = __builtin_amdgcn_exp2f(SB[4 * r + 2] - MRUN);        \
        SB[4 * r + 3] = __builtin_amdgcn_exp2f(SB[4 * r + 3] - MRUN);        \
        rs0 += SB[4 * r + 0]; rs1 += SB[4 * r + 1];                          \
        rs2 += SB[4 * r + 2]; rs3 += SB[4 * r + 3];                          \
      }                                                                      \
      float rs = (rs0 + rs1) + (rs2 + rs3);                                  \
      rs += __shfl_xor(rs, 32);                                              \
      LRUN += rs;                                                            \
      MKFRAG(SA, 0, PFR[0]) MKFRAG(SA, 8, PFR[1])                            \
      MKFRAG(SB, 0, PFR[2]) MKFRAG(SB, 8, PFR[3])                            \
    }

    SOFTMAX_FRAG(sAh, sBh, mB, lB, oAh, oBh, pfh)
    if (lowAct) {
      SOFTMAX_FRAG(sAl, sBl, mA, lA, oAl, oBl, pfl)
    }
#undef SOFTMAX_FRAG
#undef MKFRAG

    // ---- PV: vf reads shared across both q-groups ----
    __builtin_amdgcn_s_setprio(1);
    if (lowAct) {
#pragma unroll
      for (int ks = 0; ks < 4; ++ks) {
        const int vbo = (32 * ks + 16 * hi) ^ swz;
        bf16x8 vf0 = *(const bf16x8*)((const char*)bV + l31 * 128 + vbo);
        bf16x8 vf1 = *(const bf16x8*)((const char*)bV + (32 + l31) * 128 + vbo);
        oAh = __builtin_amdgcn_mfma_f32_32x32x16_bf16(vf0, pfh[ks], oAh, 0, 0, 0);
        oBh = __builtin_amdgcn_mfma_f32_32x32x16_bf16(vf1, pfh[ks], oBh, 0, 0, 0);
        oAl = __builtin_amdgcn_mfma_f32_32x32x16_bf16(vf0, pfl[ks], oAl, 0, 0, 0);
        oBl = __builtin_amdgcn_mfma_f32_32x32x16_bf16(vf1, pfl[ks], oBl, 0, 0, 0);
      }
    } else {
#pragma unroll
      for (int ks = 0; ks < 4; ++ks) {
        const int vbo = (32 * ks + 16 * hi) ^ swz;
        bf16x8 vf0 = *(const bf16x8*)((const char*)bV + l31 * 128 + vbo);
        bf16x8 vf1 = *(const bf16x8*)((const char*)bV + (32 + l31) * 128 + vbo);
        oAh = __builtin_amdgcn_mfma_f32_32x32x16_bf16(vf0, pfh[ks], oAh, 0, 0, 0);
        oBh = __builtin_amdgcn_mfma_f32_32x32x16_bf16(vf1, pfh[ks], oBh, 0, 0, 0);
      }
    }
    __builtin_amdgcn_s_setprio(0);
  }

  // ---- epilogue: both q-groups; lane owns one row, d = crow(r,hi)+32dt ----
#pragma unroll
  for (int grp = 0; grp < 2; ++grp) {
    const float inv = 1.f / (grp ? lB : lA);
    float* orow = Op + (size_t)(grp ? igB : igA) * HD;
    const f32x16& xA = grp ? oAh : oAl;
    const f32x16& xB = grp ? oBh : oBl;
#pragma unroll
    for (int q2 = 0; q2 < 4; ++q2) {
      float4 o;
      o.x = xA[4 * q2 + 0] * inv; o.y = xA[4 * q2 + 1] * inv;
      o.z = xA[4 * q2 + 2] * inv; o.w = xA[4 * q2 + 3] * inv;
      *(float4*)(orow + 8 * q2 + 4 * hi) = o;
      float4 pq;
      pq.x = xB[4 * q2 + 0] * inv; pq.y = xB[4 * q2 + 1] * inv;
      pq.z = xB[4 * q2 + 2] * inv; pq.w = xB[4 * q2 + 3] * inv;
      *(float4*)(orow + 32 + 8 * q2 + 4 * hi) = pq;
    }
  }
}

// ---------------------------------------------------------------------------
// Fallback (verified round-1 kernel) in case ws_size is too small.
// ---------------------------------------------------------------------------
__global__ void fattn_fallback(const float* __restrict__ Q,
                               const float* __restrict__ K,
                               const float* __restrict__ V,
                               float* __restrict__ O) {
  __shared__ __align__(16) unsigned short sK[64 * 64];
  __shared__ __align__(16) unsigned short sVt[64 * 72];
  __shared__ __align__(16) unsigned short sP[4][16 * 72];

  const int tid = threadIdx.x;
  const int wid = tid >> 6;
  const int lane = tid & 63;
  const int g = lane >> 4;
  const int lx = lane & 15;

  const int qb = (int)gridDim.x - 1 - (int)blockIdx.x;
  const int bh = blockIdx.y;
  const int q0 = qb * 64;

  const size_t base = (size_t)bh * SEQ * HD;
  const float* Qp = Q + base;
  const float* Kp = K + base;
  const float* Vp = V + base;
  float* Op = O + base;

  bf16x8 qf[2];
  {
    const int row = q0 + wid * 16 + lx;
    const float* qr = Qp + (size_t)row * HD + 8 * g;
#pragma unroll
    for (int c = 0; c < 2; ++c) {
      float4 a = *(const float4*)(qr + 32 * c);
      float4 b = *(const float4*)(qr + 32 * c + 4);
      bf16x8 w;
      w[0] = (__bf16)(a.x * 0.125f); w[1] = (__bf16)(a.y * 0.125f);
      w[2] = (__bf16)(a.z * 0.125f); w[3] = (__bf16)(a.w * 0.125f);
      w[4] = (__bf16)(b.x * 0.125f); w[5] = (__bf16)(b.y * 0.125f);
      w[6] = (__bf16)(b.z * 0.125f); w[7] = (__bf16)(b.w * 0.125f);
      qf[c] = w;
    }
  }

  f32x4 acc[4];
#pragma unroll
  for (int dt = 0; dt < 4; ++dt) acc[dt] = (f32x4){0.f, 0.f, 0.f, 0.f};
  float m_run[4], l_run[4];
#pragma unroll
  for (int r = 0; r < 4; ++r) { m_run[r] = -1e30f; l_run[r] = 0.f; }

  const int iw0 = q0 + wid * 16;
  const int nkb = qb + 1;

  for (int kb = 0; kb < nkb; ++kb) {
    const int j0 = kb * 64;
    __syncthreads();
    {
      const int jr = tid >> 2;
      const int d0 = (tid & 3) * 16;
      const float* src = Kp + (size_t)(j0 + jr) * HD + d0;
#pragma unroll
      for (int h = 0; h < 2; ++h) {
        bf16x8 w = cvt8(src + 8 * h);
        const int byteoff = ((d0 + 8 * h) * 2) ^ ((jr & 7) << 4);
        *(bf16x8*)((char*)sK + jr * 128 + byteoff) = w;
      }
      const float* vsrc = Vp + (size_t)(j0 + jr) * HD + d0;
#pragma unroll
      for (int h = 0; h < 4; ++h) {
        float4 a = *(const float4*)(vsrc + 4 * h);
        sVt[(d0 + 4 * h + 0) * 72 + jr] = __builtin_bit_cast(unsigned short, (__bf16)a.x);
        sVt[(d0 + 4 * h + 1) * 72 + jr] = __builtin_bit_cast(unsigned short, (__bf16)a.y);
        sVt[(d0 + 4 * h + 2) * 72 + jr] = __builtin_bit_cast(unsigned short, (__bf16)a.z);
        sVt[(d0 + 4 * h + 3) * 72 + jr] = __builtin_bit_cast(unsigned short, (__bf16)a.w);
      }
    }
    __syncthreads();

    float s[4][4];
#pragma unroll
    for (int jt = 0; jt < 4; ++jt) {
      f32x4 c = (f32x4){0.f, 0.f, 0.f, 0.f};
#pragma unroll
      for (int cc = 0; cc < 2; ++cc) {
        const int row = jt * 16 + lx;
        const int byteoff = (16 * g + 64 * cc) ^ ((row & 7) << 4);
        bf16x8 kf = *(const bf16x8*)((const char*)sK + row * 128 + byteoff);
        c = __builtin_amdgcn_mfma_f32_16x16x32_bf16(qf[cc], kf, c, 0, 0, 0);
      }
      const int jg = j0 + jt * 16 + lx;
#pragma unroll
      for (int r = 0; r < 4; ++r) {
        const int igf = iw0 + 4 * g + r;
        s[jt][r] = (jg <= igf) ? c[r] : -1e30f;
      }
    }

#pragma unroll
    for (int r = 0; r < 4; ++r) {
      float mt = fmaxf(fmaxf(s[0][r], s[1][r]), fmaxf(s[2][r], s[3][r]));
#pragma unroll
      for (int msk = 1; msk <= 8; msk <<= 1) mt = fmaxf(mt, __shfl_xor(mt, msk));
      const float mn = fmaxf(m_run[r], mt);
      const float alpha = __expf(m_run[r] - mn);
      m_run[r] = mn;
      float rs = 0.f;
#pragma unroll
      for (int jt = 0; jt < 4; ++jt) {
        const float pv = __expf(s[jt][r] - mn);
        s[jt][r] = pv;
        rs += pv;
      }
#pragma unroll
      for (int msk = 1; msk <= 8; msk <<= 1) rs += __shfl_xor(rs, msk);
      l_run[r] = l_run[r] * alpha + rs;
#pragma unroll
      for (int dt = 0; dt < 4; ++dt) acc[dt][r] *= alpha;
    }

#pragma unroll
    for (int jt = 0; jt < 4; ++jt)
#pragma unroll
      for (int r = 0; r < 4; ++r)
        sP[wid][(4 * g + r) * 72 + jt * 16 + lx] =
            __builtin_bit_cast(unsigned short, (__bf16)s[jt][r]);
    asm volatile("s_waitcnt lgkmcnt(0)" ::: "memory");

#pragma unroll
    for (int cc = 0; cc < 2; ++cc) {
      bf16x8 pf = *(const bf16x8*)(&sP[wid][lx * 72 + 8 * g + 32 * cc]);
#pragma unroll
      for (int dt = 0; dt < 4; ++dt) {
        bf16x8 vf = *(const bf16x8*)(&sVt[(lx + 16 * dt) * 72 + 8 * g + 32 * cc]);
        acc[dt] = __builtin_amdgcn_mfma_f32_16x16x32_bf16(pf, vf, acc[dt], 0, 0, 0);
      }
    }
  }

#pragma unroll
  for (int r = 0; r < 4; ++r) {
    const float inv = 1.f / l_run[r];
    const int igf = q0 + wid * 16 + 4 * g + r;
    float* orow = Op + (size_t)igf * HD + lx;
#pragma unroll
    for (int dt = 0; dt < 4; ++dt) orow[16 * dt] = acc[dt][r] * inv;
  }
}

extern "C" void kernel_launch(void* const* d_in, const int* in_sizes, int n_in,
                              void* d_out, int out_size, void* d_ws, size_t ws_size,
                              hipStream_t stream) {
  const float* q = (const float*)d_in[0];
  const float* k = (const float*)d_in[1];
  const float* v = (const float*)d_in[2];
  float* o = (float*)d_out;

  const size_t kv_elems = (size_t)64 * SEQ * HD;
  const size_t need = 2 * kv_elems * sizeof(unsigned short);  // 32 MiB

  if (ws_size >= need) {
    unsigned short* kswz = (unsigned short*)d_ws;
    unsigned short* vt = kswz + kv_elems;
    dim3 pgrid(SEQ / 64, 64);
    prep_kernel<<<pgrid, 256, 0, stream>>>(k, v, kswz, vt);
    dim3 grid(NQB / 2, 64);  // paired q-tiles: uniform work
    fattn_kernel<<<grid, 256, 0, stream>>>(q, kswz, vt, o);
  } else {
    dim3 grid(SEQ / 64, 64);
    fattn_fallback<<<grid, 256, 0, stream>>>(q, k, v, o);
  }
}

// Round 8
// 85.705 us; speedup vs baseline: 3.2468x; 1.0371x over previous
//
#include <hip/hip_runtime.h>
#include <hip/hip_bf16.h>

#define SEQ 2048
#define HD 64
#define NQB (SEQ / 128)  // 16 q-tiles of 128 rows

typedef __bf16 bf16x8 __attribute__((ext_vector_type(8)));
typedef float f32x4 __attribute__((ext_vector_type(4)));
typedef float f32x16 __attribute__((ext_vector_type(16)));
typedef unsigned int u32x4 __attribute__((ext_vector_type(4)));

typedef const __attribute__((address_space(1))) void gvoid_t;
typedef __attribute__((address_space(3))) void svoid_t;

__device__ __forceinline__ void gload_lds16(const void* g, void* l) {
  __builtin_amdgcn_global_load_lds((gvoid_t*)g, (svoid_t*)l, 16, 0, 0);
}

__device__ __forceinline__ bf16x8 cvt8(const float* p) {
  float4 a = *(const float4*)p;
  float4 b = *(const float4*)(p + 4);
  bf16x8 w;
  w[0] = (__bf16)a.x; w[1] = (__bf16)a.y; w[2] = (__bf16)a.z; w[3] = (__bf16)a.w;
  w[4] = (__bf16)b.x; w[5] = (__bf16)b.y; w[6] = (__bf16)b.z; w[7] = (__bf16)b.w;
  return w;
}

__device__ __forceinline__ unsigned cvtpk_bf16(float lo, float hi) {
  unsigned r;
  asm("v_cvt_pk_bf16_f32 %0, %1, %2" : "=v"(r) : "v"(lo), "v"(hi));
  return r;
}

// pairwise-tree max over an f32x16 (short dep chains) -- verified
__device__ __forceinline__ float tmax16(const f32x16& v) {
  float a0 = fmaxf(v[0], v[1]), a1 = fmaxf(v[2], v[3]);
  float a2 = fmaxf(v[4], v[5]), a3 = fmaxf(v[6], v[7]);
  float a4 = fmaxf(v[8], v[9]), a5 = fmaxf(v[10], v[11]);
  float a6 = fmaxf(v[12], v[13]), a7 = fmaxf(v[14], v[15]);
  float b0 = fmaxf(a0, a1), b1 = fmaxf(a2, a3), b2 = fmaxf(a4, a5), b3 = fmaxf(a6, a7);
  return fmaxf(fmaxf(b0, b1), fmaxf(b2, b3));
}

// ---------------------------------------------------------------------------
// Pre-pass (verified R2-R7): K -> bf16 swizzled rows; V -> V^T bf16
// [bh][d][SEQ] with per-64-j-segment swizzle keyed on (d&7).
// ---------------------------------------------------------------------------
__global__ void prep_kernel(const float* __restrict__ K,
                            const float* __restrict__ V,
                            unsigned short* __restrict__ Kswz,
                            unsigned short* __restrict__ Vt) {
  __shared__ __align__(16) unsigned short sT[64 * 72];
  const int t = threadIdx.x;
  const int kb = blockIdx.x;
  const int bh = blockIdx.y;
  const int j0 = kb * 64;
  const size_t ibase = (size_t)bh * SEQ * HD;

  {
    const int j = t >> 2;
    const int m = (t & 3) * 2;
    const float* src = K + ibase + (size_t)(j0 + j) * HD + m * 8;
    unsigned short* dst = Kswz + ibase + (size_t)(j0 + j) * HD;
#pragma unroll
    for (int h = 0; h < 2; ++h) {
      bf16x8 w = cvt8(src + 8 * h);
      const int c = (m + h) ^ (j & 7);
      *(bf16x8*)(dst + c * 8) = w;
    }
  }
  {
    const int jr = t >> 2;
    const int d0 = (t & 3) * 16;
    const float* vsrc = V + ibase + (size_t)(j0 + jr) * HD + d0;
#pragma unroll
    for (int h = 0; h < 4; ++h) {
      float4 a = *(const float4*)(vsrc + 4 * h);
      sT[(d0 + 4 * h + 0) * 72 + jr] = __builtin_bit_cast(unsigned short, (__bf16)a.x);
      sT[(d0 + 4 * h + 1) * 72 + jr] = __builtin_bit_cast(unsigned short, (__bf16)a.y);
      sT[(d0 + 4 * h + 2) * 72 + jr] = __builtin_bit_cast(unsigned short, (__bf16)a.z);
      sT[(d0 + 4 * h + 3) * 72 + jr] = __builtin_bit_cast(unsigned short, (__bf16)a.w);
    }
  }
  __syncthreads();
  {
#pragma unroll
    for (int p = 0; p < 2; ++p) {
      const int cid = t + 256 * p;
      const int d = cid >> 3;
      const int jj = cid & 7;
      bf16x8 w = *(const bf16x8*)(&sT[d * 72 + 8 * jj]);
      const int c = jj ^ (d & 7);
      *(bf16x8*)(Vt + (size_t)bh * HD * SEQ + (size_t)d * SEQ + j0 + c * 8) = w;
    }
  }
}

// ---------------------------------------------------------------------------
// Main: paired-q swapped-operand 32x32 MFMA flash attention.
// Block = 4 waves, q-tiles qbA=p and qbB=NQB-1-p. KV tiles of 64;
// R8: TWO tiles per barrier, 4-buffer LDS ring (R5 structure), with the
// verified shfl_xor reductions (xmax/xadd asm removed for good) + z16 peel.
// ---------------------------------------------------------------------------
__global__ __launch_bounds__(256, 2) void fattn_kernel(
    const float* __restrict__ Q, const unsigned short* __restrict__ Kswz,
    const unsigned short* __restrict__ Vt, float* __restrict__ O) {
  __shared__ __align__(16) unsigned short sbuf[4][2 * 64 * 64];  // K | V^T

  const int tid = threadIdx.x;
  const int wid = tid >> 6;
  const int lane = tid & 63;
  const int l31 = lane & 31;
  const int hi = lane >> 5;

  const int p = blockIdx.x;     // 0..NQB/2-1
  const int qbA = p;            // low q-tile
  const int qbB = NQB - 1 - p;  // high q-tile
  const int bh = blockIdx.y;

  const int i0A = qbA * 128 + wid * 32;
  const int i0B = qbB * 128 + wid * 32;
  const int igA = i0A + l31;
  const int igB = i0B + l31;

  const float* Qp = Q + (size_t)bh * SEQ * HD;
  const unsigned short* Kg = Kswz + (size_t)bh * SEQ * HD;
  const unsigned short* Vg = Vt + (size_t)bh * HD * SEQ;
  float* Op = O + (size_t)bh * SEQ * HD;

  // ---- Q fragments (B-operand layout), scale*log2e folded ----
  const float qscale = 0.125f * 1.44269504088896340736f;
  bf16x8 qfA[4], qfB[4];
#pragma unroll
  for (int grp = 0; grp < 2; ++grp) {
    const float* qr = Qp + (size_t)(grp ? igB : igA) * HD + 8 * hi;
#pragma unroll
    for (int c = 0; c < 4; ++c) {
      float4 a = *(const float4*)(qr + 16 * c);
      float4 b = *(const float4*)(qr + 16 * c + 4);
      bf16x8 w;
      w[0] = (__bf16)(a.x * qscale); w[1] = (__bf16)(a.y * qscale);
      w[2] = (__bf16)(a.z * qscale); w[3] = (__bf16)(a.w * qscale);
      w[4] = (__bf16)(b.x * qscale); w[5] = (__bf16)(b.y * qscale);
      w[6] = (__bf16)(b.z * qscale); w[7] = (__bf16)(b.w * qscale);
      if (grp) qfB[c] = w; else qfA[c] = w;
    }
  }

  // persistent zero C-operand (verified R7)
  f32x16 z16;
#pragma unroll
  for (int r = 0; r < 16; ++r) z16[r] = 0.f;

  f32x16 oAl, oBl, oAh, oBh;
#pragma unroll
  for (int r = 0; r < 16; ++r) { oAl[r] = 0.f; oBl[r] = 0.f; oAh[r] = 0.f; oBh[r] = 0.f; }
  float mA = -1e30f, lA = 0.f, mB = -1e30f, lB = 0.f;

  const int totTiles = 2 * qbB + 2;  // 64-row KV tiles needed by high group
  const int nIter = qbB + 1;         // two tiles per iteration

  auto stage = [&](int tile) {
    unsigned short* base = &sbuf[0][0] + (size_t)(tile & 3) * 8192;
    const int j0s = tile * 64;
#pragma unroll
    for (int tt = 0; tt < 2; ++tt) {
      const int row = 16 * wid + 8 * tt;  // uniform per wave
      const unsigned short* gk =
          Kg + (size_t)(j0s + row + (lane >> 3)) * HD + (lane & 7) * 8;
      gload_lds16(gk, base + row * HD);
      const unsigned short* gv =
          Vg + (size_t)(row + (lane >> 3)) * SEQ + j0s + (lane & 7) * 8;
      gload_lds16(gv, base + 4096 + row * HD);
    }
  };

  const int swz = (l31 & 7) << 4;

  auto processTile = [&](int tile, bool dual) {
    const int j0 = tile * 64;
    const unsigned short* base = &sbuf[0][0] + (size_t)(tile & 3) * 8192;
    const unsigned short* bK = base;
    const unsigned short* bV = base + 4096;

    f32x16 sAl, sBl, sAh, sBh;

    // ---- QK^T (swapped): kf reads shared across both q-groups ----
    __builtin_amdgcn_s_setprio(1);
    {  // c = 0 peeled: C-operand = persistent z16
      const int boff = (16 * hi) ^ swz;
      bf16x8 kf0 = *(const bf16x8*)((const char*)bK + l31 * 128 + boff);
      bf16x8 kf1 = *(const bf16x8*)((const char*)bK + (32 + l31) * 128 + boff);
      sAh = __builtin_amdgcn_mfma_f32_32x32x16_bf16(kf0, qfB[0], z16, 0, 0, 0);
      sBh = __builtin_amdgcn_mfma_f32_32x32x16_bf16(kf1, qfB[0], z16, 0, 0, 0);
      if (dual) {
        sAl = __builtin_amdgcn_mfma_f32_32x32x16_bf16(kf0, qfA[0], z16, 0, 0, 0);
        sBl = __builtin_amdgcn_mfma_f32_32x32x16_bf16(kf1, qfA[0], z16, 0, 0, 0);
      } else {
        sAl = z16; sBl = z16;
      }
    }
#pragma unroll
    for (int c = 1; c < 4; ++c) {
      const int boff = (32 * c + 16 * hi) ^ swz;
      bf16x8 kf0 = *(const bf16x8*)((const char*)bK + l31 * 128 + boff);
      bf16x8 kf1 = *(const bf16x8*)((const char*)bK + (32 + l31) * 128 + boff);
      sAh = __builtin_amdgcn_mfma_f32_32x32x16_bf16(kf0, qfB[c], sAh, 0, 0, 0);
      sBh = __builtin_amdgcn_mfma_f32_32x32x16_bf16(kf1, qfB[c], sBh, 0, 0, 0);
      if (dual) {
        sAl = __builtin_amdgcn_mfma_f32_32x32x16_bf16(kf0, qfA[c], sAl, 0, 0, 0);
        sBl = __builtin_amdgcn_mfma_f32_32x32x16_bf16(kf1, qfA[c], sBl, 0, 0, 0);
      }
    }
    __builtin_amdgcn_s_setprio(0);

    // ---- causal masks (diagonal tiles only; wave-uniform tests) ----
    if (j0 + 63 > i0B) {
#pragma unroll
      for (int r = 0; r < 16; ++r) {
        const int jl = j0 + (r & 3) + 8 * (r >> 2) + 4 * hi;
        sAh[r] = (jl <= igB) ? sAh[r] : -1e30f;
        sBh[r] = (jl + 32 <= igB) ? sBh[r] : -1e30f;
      }
    }
    if (dual && (j0 + 63 > i0A)) {
#pragma unroll
      for (int r = 0; r < 16; ++r) {
        const int jl = j0 + (r & 3) + 8 * (r >> 2) + 4 * hi;
        sAl[r] = (jl <= igA) ? sAl[r] : -1e30f;
        sBl[r] = (jl + 32 <= igA) ? sBl[r] : -1e30f;
      }
    }

    // ---- softmax + PV-fragment build, per group (verified reductions) ----
    bf16x8 pfh[4], pfl[4];

#define MKFRAG(SV, BASE, DST)                                                \
    {                                                                        \
      unsigned a0 = cvtpk_bf16(SV[BASE + 0], SV[BASE + 1]);                  \
      unsigned b0 = cvtpk_bf16(SV[BASE + 4], SV[BASE + 5]);                  \
      asm("v_permlane32_swap_b32 %0, %1" : "+v"(a0), "+v"(b0));              \
      unsigned a1 = cvtpk_bf16(SV[BASE + 2], SV[BASE + 3]);                  \
      unsigned b1 = cvtpk_bf16(SV[BASE + 6], SV[BASE + 7]);                  \
      asm("v_permlane32_swap_b32 %0, %1" : "+v"(a1), "+v"(b1));              \
      u32x4 wv = {a0, a1, b0, b1};                                           \
      DST = __builtin_bit_cast(bf16x8, wv);                                  \
    }

#define SOFTMAX_FRAG(SA, SB, MRUN, LRUN, OA, OB, PFR)                        \
    {                                                                        \
      float pmax = fmaxf(tmax16(SA), tmax16(SB));                            \
      pmax = fmaxf(pmax, __shfl_xor(pmax, 32));                              \
      if (!__all(pmax - MRUN <= 10.0f)) {                                    \
        const float mn = fmaxf(MRUN, pmax);                                  \
        const float al = __builtin_amdgcn_exp2f(MRUN - mn);                  \
        MRUN = mn;                                                           \
        LRUN *= al;                                                          \
        _Pragma("unroll")                                                    \
        for (int r = 0; r < 16; ++r) { OA[r] *= al; OB[r] *= al; }           \
      }                                                                      \
      float rs0 = 0.f, rs1 = 0.f, rs2 = 0.f, rs3 = 0.f;                      \
      _Pragma("unroll")                                                      \
      for (int r = 0; r < 4; ++r) {                                          \
        SA[4 * r + 0] = __builtin_amdgcn_exp2f(SA[4 * r + 0] - MRUN);        \
        SA[4 * r + 1] = __builtin_amdgcn_exp2f(SA[4 * r + 1] - MRUN);        \
        SA[4 * r + 2] = __builtin_amdgcn_exp2f(SA[4 * r + 2] - MRUN);        \
        SA[4 * r + 3] = __builtin_amdgcn_exp2f(SA[4 * r + 3] - MRUN);        \
        rs0 += SA[4 * r + 0]; rs1 += SA[4 * r + 1];                          \
        rs2 += SA[4 * r + 2]; rs3 += SA[4 * r + 3];                          \
      }                                                                      \
      _Pragma("unroll")                                                      \
      for (int r = 0; r < 4; ++r) {                                          \
        SB[4 * r + 0] = __builtin_amdgcn_exp2f(SB[4 * r + 0] - MRUN);        \
        SB[4 * r + 1] = __builtin_amdgcn_exp2f(SB[4 * r + 1] - MRUN);        \
        SB[4 * r + 2] = __builtin_amdgcn_exp2f(SB[4 * r + 2] - MRUN);        \
        SB[4 * r + 3] = __builtin_amdgcn_exp2f(SB[4 * r + 3] - MRUN);        \
        rs0 += SB[4 * r + 0]; rs1 += SB[4 * r + 1];                          \
        rs2 += SB[4 * r + 2]; rs3 += SB[4 * r + 3];                          \
      }                                                                      \
      float rs = (rs0 + rs1) + (rs2 + rs3);                                  \
      rs += __shfl_xor(rs, 32);                                              \
      LRUN += rs;                                                            \
      MKFRAG(SA, 0, PFR[0]) MKFRAG(SA, 8, PFR[1])                            \
      MKFRAG(SB, 0, PFR[2]) MKFRAG(SB, 8, PFR[3])                            \
    }

    SOFTMAX_FRAG(sAh, sBh, mB, lB, oAh, oBh, pfh)
    if (dual) {
      SOFTMAX_FRAG(sAl, sBl, mA, lA, oAl, oBl, pfl)
    }
#undef SOFTMAX_FRAG
#undef MKFRAG

    // ---- PV: vf reads shared across both q-groups ----
    __builtin_amdgcn_s_setprio(1);
    if (dual) {
#pragma unroll
      for (int ks = 0; ks < 4; ++ks) {
        const int vbo = (32 * ks + 16 * hi) ^ swz;
        bf16x8 vf0 = *(const bf16x8*)((const char*)bV + l31 * 128 + vbo);
        bf16x8 vf1 = *(const bf16x8*)((const char*)bV + (32 + l31) * 128 + vbo);
        oAh = __builtin_amdgcn_mfma_f32_32x32x16_bf16(vf0, pfh[ks], oAh, 0, 0, 0);
        oBh = __builtin_amdgcn_mfma_f32_32x32x16_bf16(vf1, pfh[ks], oBh, 0, 0, 0);
        oAl = __builtin_amdgcn_mfma_f32_32x32x16_bf16(vf0, pfl[ks], oAl, 0, 0, 0);
        oBl = __builtin_amdgcn_mfma_f32_32x32x16_bf16(vf1, pfl[ks], oBl, 0, 0, 0);
      }
    } else {
#pragma unroll
      for (int ks = 0; ks < 4; ++ks) {
        const int vbo = (32 * ks + 16 * hi) ^ swz;
        bf16x8 vf0 = *(const bf16x8*)((const char*)bV + l31 * 128 + vbo);
        bf16x8 vf1 = *(const bf16x8*)((const char*)bV + (32 + l31) * 128 + vbo);
        oAh = __builtin_amdgcn_mfma_f32_32x32x16_bf16(vf0, pfh[ks], oAh, 0, 0, 0);
        oBh = __builtin_amdgcn_mfma_f32_32x32x16_bf16(vf1, pfh[ks], oBh, 0, 0, 0);
      }
    }
    __builtin_amdgcn_s_setprio(0);
  };

  // ---- main loop: 2 tiles per barrier; next pair staged after barrier ----
  stage(0);
  stage(1);

  for (int t = 0; t < nIter; ++t) {
    asm volatile("s_waitcnt vmcnt(0)" ::: "memory");  // pair (2t,2t+1) ready
    __builtin_amdgcn_s_barrier();
    __builtin_amdgcn_sched_barrier(0);
    const int s0 = 2 * t + 2;
    if (s0 < totTiles) {
      stage(s0);
      stage(s0 + 1);
    }
    const bool dual = (t <= qbA);
    processTile(2 * t, dual);
    processTile(2 * t + 1, dual);
  }

  // ---- epilogue: both q-groups; lane owns one row, d = crow(r,hi)+32dt ----
#pragma unroll
  for (int grp = 0; grp < 2; ++grp) {
    const float inv = 1.f / (grp ? lB : lA);
    float* orow = Op + (size_t)(grp ? igB : igA) * HD;
    const f32x16& xA = grp ? oAh : oAl;
    const f32x16& xB = grp ? oBh : oBl;
#pragma unroll
    for (int q2 = 0; q2 < 4; ++q2) {
      float4 o;
      o.x = xA[4 * q2 + 0] * inv; o.y = xA[4 * q2 + 1] * inv;
      o.z = xA[4 * q2 + 2] * inv; o.w = xA[4 * q2 + 3] * inv;
      *(float4*)(orow + 8 * q2 + 4 * hi) = o;
      float4 pq;
      pq.x = xB[4 * q2 + 0] * inv; pq.y = xB[4 * q2 + 1] * inv;
      pq.z = xB[4 * q2 + 2] * inv; pq.w = xB[4 * q2 + 3] * inv;
      *(float4*)(orow + 32 + 8 * q2 + 4 * hi) = pq;
    }
  }
}

// ---------------------------------------------------------------------------
// Fallback (verified round-1 kernel) in case ws_size is too small.
// ---------------------------------------------------------------------------
__global__ void fattn_fallback(const float* __restrict__ Q,
                               const float* __restrict__ K,
                               const float* __restrict__ V,
                               float* __restrict__ O) {
  __shared__ __align__(16) unsigned short sK[64 * 64];
  __shared__ __align__(16) unsigned short sVt[64 * 72];
  __shared__ __align__(16) unsigned short sP[4][16 * 72];

  const int tid = threadIdx.x;
  const int wid = tid >> 6;
  const int lane = tid & 63;
  const int g = lane >> 4;
  const int lx = lane & 15;

  const int qb = (int)gridDim.x - 1 - (int)blockIdx.x;
  const int bh = blockIdx.y;
  const int q0 = qb * 64;

  const size_t base = (size_t)bh * SEQ * HD;
  const float* Qp = Q + base;
  const float* Kp = K + base;
  const float* Vp = V + base;
  float* Op = O + base;

  bf16x8 qf[2];
  {
    const int row = q0 + wid * 16 + lx;
    const float* qr = Qp + (size_t)row * HD + 8 * g;
#pragma unroll
    for (int c = 0; c < 2; ++c) {
      float4 a = *(const float4*)(qr + 32 * c);
      float4 b = *(const float4*)(qr + 32 * c + 4);
      bf16x8 w;
      w[0] = (__bf16)(a.x * 0.125f); w[1] = (__bf16)(a.y * 0.125f);
      w[2] = (__bf16)(a.z * 0.125f); w[3] = (__bf16)(a.w * 0.125f);
      w[4] = (__bf16)(b.x * 0.125f); w[5] = (__bf16)(b.y * 0.125f);
      w[6] = (__bf16)(b.z * 0.125f); w[7] = (__bf16)(b.w * 0.125f);
      qf[c] = w;
    }
  }

  f32x4 acc[4];
#pragma unroll
  for (int dt = 0; dt < 4; ++dt) acc[dt] = (f32x4){0.f, 0.f, 0.f, 0.f};
  float m_run[4], l_run[4];
#pragma unroll
  for (int r = 0; r < 4; ++r) { m_run[r] = -1e30f; l_run[r] = 0.f; }

  const int iw0 = q0 + wid * 16;
  const int nkb = qb + 1;

  for (int kb = 0; kb < nkb; ++kb) {
    const int j0 = kb * 64;
    __syncthreads();
    {
      const int jr = tid >> 2;
      const int d0 = (tid & 3) * 16;
      const float* src = Kp + (size_t)(j0 + jr) * HD + d0;
#pragma unroll
      for (int h = 0; h < 2; ++h) {
        bf16x8 w = cvt8(src + 8 * h);
        const int byteoff = ((d0 + 8 * h) * 2) ^ ((jr & 7) << 4);
        *(bf16x8*)((char*)sK + jr * 128 + byteoff) = w;
      }
      const float* vsrc = Vp + (size_t)(j0 + jr) * HD + d0;
#pragma unroll
      for (int h = 0; h < 4; ++h) {
        float4 a = *(const float4*)(vsrc + 4 * h);
        sVt[(d0 + 4 * h + 0) * 72 + jr] = __builtin_bit_cast(unsigned short, (__bf16)a.x);
        sVt[(d0 + 4 * h + 1) * 72 + jr] = __builtin_bit_cast(unsigned short, (__bf16)a.y);
        sVt[(d0 + 4 * h + 2) * 72 + jr] = __builtin_bit_cast(unsigned short, (__bf16)a.z);
        sVt[(d0 + 4 * h + 3) * 72 + jr] = __builtin_bit_cast(unsigned short, (__bf16)a.w);
      }
    }
    __syncthreads();

    float s[4][4];
#pragma unroll
    for (int jt = 0; jt < 4; ++jt) {
      f32x4 c = (f32x4){0.f, 0.f, 0.f, 0.f};
#pragma unroll
      for (int cc = 0; cc < 2; ++cc) {
        const int row = jt * 16 + lx;
        const int byteoff = (16 * g + 64 * cc) ^ ((row & 7) << 4);
        bf16x8 kf = *(const bf16x8*)((const char*)sK + row * 128 + byteoff);
        c = __builtin_amdgcn_mfma_f32_16x16x32_bf16(qf[cc], kf, c, 0, 0, 0);
      }
      const int jg = j0 + jt * 16 + lx;
#pragma unroll
      for (int r = 0; r < 4; ++r) {
        const int igf = iw0 + 4 * g + r;
        s[jt][r] = (jg <= igf) ? c[r] : -1e30f;
      }
    }

#pragma unroll
    for (int r = 0; r < 4; ++r) {
      float mt = fmaxf(fmaxf(s[0][r], s[1][r]), fmaxf(s[2][r], s[3][r]));
#pragma unroll
      for (int msk = 1; msk <= 8; msk <<= 1) mt = fmaxf(mt, __shfl_xor(mt, msk));
      const float mn = fmaxf(m_run[r], mt);
      const float alpha = __expf(m_run[r] - mn);
      m_run[r] = mn;
      float rs = 0.f;
#pragma unroll
      for (int jt = 0; jt < 4; ++jt) {
        const float pv = __expf(s[jt][r] - mn);
        s[jt][r] = pv;
        rs += pv;
      }
#pragma unroll
      for (int msk = 1; msk <= 8; msk <<= 1) rs += __shfl_xor(rs, msk);
      l_run[r] = l_run[r] * alpha + rs;
#pragma unroll
      for (int dt = 0; dt < 4; ++dt) acc[dt][r] *= alpha;
    }

#pragma unroll
    for (int jt = 0; jt < 4; ++jt)
#pragma unroll
      for (int r = 0; r < 4; ++r)
        sP[wid][(4 * g + r) * 72 + jt * 16 + lx] =
            __builtin_bit_cast(unsigned short, (__bf16)s[jt][r]);
    asm volatile("s_waitcnt lgkmcnt(0)" ::: "memory");

#pragma unroll
    for (int cc = 0; cc < 2; ++cc) {
      bf16x8 pf = *(const bf16x8*)(&sP[wid][lx * 72 + 8 * g + 32 * cc]);
#pragma unroll
      for (int dt = 0; dt < 4; ++dt) {
        bf16x8 vf = *(const bf16x8*)(&sVt[(lx + 16 * dt) * 72 + 8 * g + 32 * cc]);
        acc[dt] = __builtin_amdgcn_mfma_f32_16x16x32_bf16(pf, vf, acc[dt], 0, 0, 0);
      }
    }
  }

#pragma unroll
  for (int r = 0; r < 4; ++r) {
    const float inv = 1.f / l_run[r];
    const int igf = q0 + wid * 16 + 4 * g + r;
    float* orow = Op + (size_t)igf * HD + lx;
#pragma unroll
    for (int dt = 0; dt < 4; ++dt) orow[16 * dt] = acc[dt][r] * inv;
  }
}

extern "C" void kernel_launch(void* const* d_in, const int* in_sizes, int n_in,
                              void* d_out, int out_size, void* d_ws, size_t ws_size,
                              hipStream_t stream) {
  const float* q = (const float*)d_in[0];
  const float* k = (const float*)d_in[1];
  const float* v = (const float*)d_in[2];
  float* o = (float*)d_out;

  const size_t kv_elems = (size_t)64 * SEQ * HD;
  const size_t need = 2 * kv_elems * sizeof(unsigned short);  // 32 MiB

  if (ws_size >= need) {
    unsigned short* kswz = (unsigned short*)d_ws;
    unsigned short* vt = kswz + kv_elems;
    dim3 pgrid(SEQ / 64, 64);
    prep_kernel<<<pgrid, 256, 0, stream>>>(k, v, kswz, vt);
    dim3 grid(NQB / 2, 64);  // paired q-tiles: uniform work
    fattn_kernel<<<grid, 256, 0, stream>>>(q, kswz, vt, o);
  } else {
    dim3 grid(SEQ / 64, 64);
    fattn_fallback<<<grid, 256, 0, stream>>>(q, k, v, o);
  }
}